// Round 1
// baseline (1225.067 us; speedup 1.0000x reference)
//
#include <hip/hip_runtime.h>

// FlexibleGCN forward on MI355X.
// Pipeline:
//   deg[dst]++ (atomics) -> dinv = rsqrt(deg+1)
//   hpre1 = x @ W1                      (gemm K=128)
//   agg1[dst] += dinv[s]*dinv[d]*hpre1[src]   (edge scatter, fp32 atomics)
//   h1 = relu(agg1 + dinv^2*hpre1 + b1)       (self-loop fused here)
//   hpre2 = h1 @ W2                     (gemm K=64)
//   agg2 scatter, emb = relu(agg2 + dinv^2*hpre2 + b2) -> d_out[0:N*64]
//   logits = emb @ Wfc + bfc            -> d_out[N*64:2*N*64]

constexpr int IN_DIM = 128;
constexpr int HDIM   = 64;

__global__ void deg_kernel(const int* __restrict__ dst, float* __restrict__ deg, int E) {
    int e = blockIdx.x * blockDim.x + threadIdx.x;
    if (e < E) atomicAdd(&deg[dst[e]], 1.0f);
}

__global__ void dinv_kernel(const float* __restrict__ deg, float* __restrict__ dinv, int n) {
    int i = blockIdx.x * blockDim.x + threadIdx.x;
    if (i < n) dinv[i] = rsqrtf(deg[i] + 1.0f);  // +1 = self-loop
}

// Y[n][64] = X[n][K] @ W[K][64] (+ bias). One block = 4 rows x 64 lanes.
// W staged in LDS ([k][j], j across banks -> 2-way alias = free).
template<int K, bool BIAS>
__global__ void gemm_kernel(const float* __restrict__ X, const float* __restrict__ W,
                            const float* __restrict__ bias, float* __restrict__ Y, int n) {
    __shared__ float Ws[K * 64];
    int tid = threadIdx.x;
    for (int i = tid; i < K * 64; i += 256) Ws[i] = W[i];
    __syncthreads();
    int j = tid & 63;
    int r = tid >> 6;
    int node = blockIdx.x * 4 + r;
    if (node >= n) return;
    const float* xr = X + (size_t)node * K;
    float acc = BIAS ? bias[j] : 0.0f;
#pragma unroll 8
    for (int k = 0; k < K; ++k) acc += xr[k] * Ws[k * 64 + j];
    Y[(size_t)node * 64 + j] = acc;
}

// One wave per edge; lane j handles feature j. Coalesced 256B gather of
// h[src], fp32 atomicAdd into agg[dst].
__global__ void scatter_kernel(const float* __restrict__ h, const int* __restrict__ src,
                               const int* __restrict__ dst, const float* __restrict__ dinv,
                               float* __restrict__ agg, int E) {
    int e = blockIdx.x * 4 + (threadIdx.x >> 6);
    if (e >= E) return;
    int j = threadIdx.x & 63;
    int s = src[e];
    int d = dst[e];
    float norm = dinv[s] * dinv[d];
    atomicAdd(&agg[(size_t)d * 64 + j], norm * h[(size_t)s * 64 + j]);
}

// out = relu(agg + dinv^2 * hpre + bias). In-place-safe (per-element).
__global__ void post_agg_kernel(const float* __restrict__ agg, const float* __restrict__ hpre,
                                const float* __restrict__ dinv, const float* __restrict__ bias,
                                float* __restrict__ out, int n) {
    int idx = blockIdx.x * blockDim.x + threadIdx.x;
    if (idx >= n * 64) return;
    int i = idx >> 6;
    int j = idx & 63;
    float di = dinv[i];
    float v = agg[idx] + di * di * hpre[idx] + bias[j];
    out[idx] = fmaxf(v, 0.0f);
}

extern "C" void kernel_launch(void* const* d_in, const int* in_sizes, int n_in,
                              void* d_out, int out_size, void* d_ws, size_t ws_size,
                              hipStream_t stream) {
    const float* x   = (const float*)d_in[0];
    const float* W1  = (const float*)d_in[1];
    const float* b1  = (const float*)d_in[2];
    const float* W2  = (const float*)d_in[3];
    const float* b2  = (const float*)d_in[4];
    const float* Wfc = (const float*)d_in[5];
    const float* bfc = (const float*)d_in[6];
    const int*  eidx = (const int*)d_in[7];

    const int N = in_sizes[0] / IN_DIM;     // 100000
    const int E = in_sizes[7] / 2;          // 1600000
    const int* src = eidx;
    const int* dst = eidx + E;

    // Workspace carve-up (all fp32): deg[N] | dinv[N] | bufA[N*64] | bufB[N*64]
    float* deg  = (float*)d_ws;
    float* dinv = deg  + N;
    float* bufA = dinv + N;
    float* bufB = bufA + (size_t)N * HDIM;

    float* emb    = (float*)d_out;
    float* logits = emb + (size_t)N * HDIM;

    const size_t featBytes = (size_t)N * HDIM * sizeof(float);

    // ---- degree / normalization ----
    hipMemsetAsync(deg, 0, (size_t)N * sizeof(float), stream);
    hipMemsetAsync(bufB, 0, featBytes, stream);   // agg1
    deg_kernel<<<(E + 255) / 256, 256, 0, stream>>>(dst, deg, E);
    dinv_kernel<<<(N + 255) / 256, 256, 0, stream>>>(deg, dinv, N);

    // ---- layer 1 ----
    gemm_kernel<IN_DIM, false><<<(N + 3) / 4, 256, 0, stream>>>(x, W1, nullptr, bufA, N);
    scatter_kernel<<<(E + 3) / 4, 256, 0, stream>>>(bufA, src, dst, dinv, bufB, E);
    post_agg_kernel<<<((size_t)N * HDIM + 255) / 256, 256, 0, stream>>>(bufB, bufA, dinv, b1, bufA, N);
    // bufA now holds h1

    // ---- layer 2 ----
    gemm_kernel<HDIM, false><<<(N + 3) / 4, 256, 0, stream>>>(bufA, W2, nullptr, bufB, N);
    hipMemsetAsync(bufA, 0, featBytes, stream);   // agg2
    scatter_kernel<<<(E + 3) / 4, 256, 0, stream>>>(bufB, src, dst, dinv, bufA, E);
    post_agg_kernel<<<((size_t)N * HDIM + 255) / 256, 256, 0, stream>>>(bufA, bufB, dinv, b2, emb, N);

    // ---- FC head ----
    gemm_kernel<HDIM, true><<<(N + 3) / 4, 256, 0, stream>>>(emb, Wfc, bfc, logits, N);
}

// Round 2
// 684.017 us; speedup vs baseline: 1.7910x; 1.7910x over previous
//
#include <hip/hip_runtime.h>

// FlexibleGCN forward on MI355X — Round 2: CSR gather instead of atomic scatter.
//
// Per launch:
//   cnt[dst]++  (int histogram)           -> dinv = rsqrt(cnt+1)
//   rowptr = exclusive_scan(cnt)          (3-kernel scan; also copied to fillptr)
//   esrc[rowptr[d] + fill[d]++] = src     (CSR fill, int atomics on cursors only)
//   hp1 = dinv .* (x @ W1)                (gemm, dinv folded into epilogue)
//   h1  = relu(dinv[d] * (sum_{s in N(d)} hp1[s] + hp1[d]) + b1)   (agg, register acc)
//   hp2 = dinv .* (h1 @ W2)
//   emb = relu(dinv[d] * (sum hp2[s] + hp2[d]) + b2)  -> d_out[0:N*64]
//   logits = emb @ Wfc + bfc                          -> d_out[N*64:]

constexpr int IN_DIM = 128;
constexpr int HDIM   = 64;
constexpr int SCAN_B = 1024;

// ---------- CSR build ----------

__global__ void hist_kernel(const int* __restrict__ dst, int* __restrict__ cnt, int E) {
    int e = blockIdx.x * blockDim.x + threadIdx.x;
    if (e < E) atomicAdd(&cnt[dst[e]], 1);
}

__global__ void dinv_kernel(const int* __restrict__ cnt, float* __restrict__ dinv, int n) {
    int i = blockIdx.x * blockDim.x + threadIdx.x;
    if (i < n) dinv[i] = rsqrtf((float)cnt[i] + 1.0f);  // +1 = self-loop
}

// Inclusive->exclusive per-block scan; excl written to rowptr, block totals to bsum.
__global__ void scan1_kernel(const int* __restrict__ cnt, int* __restrict__ excl,
                             int* __restrict__ bsum, int n) {
    __shared__ int sm[SCAN_B];
    int i = blockIdx.x * SCAN_B + threadIdx.x;
    int v = (i < n) ? cnt[i] : 0;
    sm[threadIdx.x] = v;
    __syncthreads();
    for (int off = 1; off < SCAN_B; off <<= 1) {
        int t = (threadIdx.x >= off) ? sm[threadIdx.x - off] : 0;
        __syncthreads();
        sm[threadIdx.x] += t;
        __syncthreads();
    }
    if (i < n) excl[i] = sm[threadIdx.x] - v;
    if (threadIdx.x == SCAN_B - 1) bsum[blockIdx.x] = sm[SCAN_B - 1];
}

// Single block: exclusive scan of block sums (nb <= 1024).
__global__ void scan2_kernel(int* __restrict__ bsum, int nb) {
    __shared__ int sm[SCAN_B];
    int v = (threadIdx.x < nb) ? bsum[threadIdx.x] : 0;
    sm[threadIdx.x] = v;
    __syncthreads();
    for (int off = 1; off < SCAN_B; off <<= 1) {
        int t = (threadIdx.x >= off) ? sm[threadIdx.x - off] : 0;
        __syncthreads();
        sm[threadIdx.x] += t;
        __syncthreads();
    }
    if (threadIdx.x < nb) bsum[threadIdx.x] = sm[threadIdx.x] - v;  // exclusive
}

// Add block offsets; duplicate result into fillptr (atomic cursors); set rowptr[n]=E.
__global__ void scan3_kernel(int* __restrict__ rowptr, const int* __restrict__ bsum,
                             int* __restrict__ fillptr, int n, int E) {
    int i = blockIdx.x * SCAN_B + threadIdx.x;
    if (i < n) {
        int v = rowptr[i] + bsum[blockIdx.x];
        rowptr[i]  = v;
        fillptr[i] = v;
    }
    if (i == 0) rowptr[n] = E;
}

__global__ void fill_kernel(const int* __restrict__ src, const int* __restrict__ dst,
                            int* __restrict__ fillptr, int* __restrict__ esrc, int E) {
    int e = blockIdx.x * blockDim.x + threadIdx.x;
    if (e < E) {
        int pos = atomicAdd(&fillptr[dst[e]], 1);
        esrc[pos] = src[e];
    }
}

// ---------- dense layers ----------

// Y[n][64] = X[n][K] @ W[K][64]; optional *dinv[row] scale, optional +bias.
// Block = 256 threads = 4 waves; each wave computes 4 rows (16 rows/block).
template<int K, bool SCALE, bool BIAS>
__global__ void gemm_kernel(const float* __restrict__ X, const float* __restrict__ W,
                            const float* __restrict__ bias, const float* __restrict__ dinv,
                            float* __restrict__ Y, int n) {
    __shared__ float Ws[K * 64];
    int tid = threadIdx.x;
    for (int i = tid; i < K * 64; i += 256) Ws[i] = W[i];
    __syncthreads();
    int j = tid & 63;
    int w = tid >> 6;
    int node0 = blockIdx.x * 16 + w * 4;
    if (node0 >= n) return;
    const float* x0 = X + (size_t)node0 * K;
    float acc0 = 0.f, acc1 = 0.f, acc2 = 0.f, acc3 = 0.f;
#pragma unroll 8
    for (int k = 0; k < K; ++k) {
        float wv = Ws[k * 64 + j];
        acc0 += x0[k]         * wv;
        acc1 += x0[K + k]     * wv;
        acc2 += x0[2 * K + k] * wv;
        acc3 += x0[3 * K + k] * wv;
    }
    float accs[4] = {acc0, acc1, acc2, acc3};
#pragma unroll
    for (int r = 0; r < 4; ++r) {
        int node = node0 + r;
        if (node < n) {
            float v = accs[r];
            if (BIAS) v += bias[j];
            if (SCALE) v *= dinv[node];
            Y[(size_t)node * 64 + j] = v;
        }
    }
}

// One wave per node: acc[j] = hp[node][j] + sum_{s in N(node)} hp[s][j]
// out = (relu?)(dinv[node]*acc + bias[j])
template<bool RELU>
__global__ void agg_kernel(const float* __restrict__ hp, const int* __restrict__ esrc,
                           const int* __restrict__ rowptr, const float* __restrict__ dinv,
                           const float* __restrict__ bias, float* __restrict__ out, int n) {
    int node = blockIdx.x * 4 + (threadIdx.x >> 6);
    if (node >= n) return;
    int j = threadIdx.x & 63;
    int beg = rowptr[node], end = rowptr[node + 1];
    float acc = hp[(size_t)node * 64 + j];  // self-loop (hp already dinv[src]-scaled)
    int k = beg;
    for (; k + 4 <= end; k += 4) {
        int s0 = esrc[k], s1 = esrc[k + 1], s2 = esrc[k + 2], s3 = esrc[k + 3];
        float v0 = hp[(size_t)s0 * 64 + j];
        float v1 = hp[(size_t)s1 * 64 + j];
        float v2 = hp[(size_t)s2 * 64 + j];
        float v3 = hp[(size_t)s3 * 64 + j];
        acc += v0 + v1 + v2 + v3;
    }
    for (; k < end; ++k) acc += hp[(size_t)esrc[k] * 64 + j];
    float v = dinv[node] * acc + bias[j];
    out[(size_t)node * 64 + j] = RELU ? fmaxf(v, 0.f) : v;
}

extern "C" void kernel_launch(void* const* d_in, const int* in_sizes, int n_in,
                              void* d_out, int out_size, void* d_ws, size_t ws_size,
                              hipStream_t stream) {
    const float* x   = (const float*)d_in[0];
    const float* W1  = (const float*)d_in[1];
    const float* b1  = (const float*)d_in[2];
    const float* W2  = (const float*)d_in[3];
    const float* b2  = (const float*)d_in[4];
    const float* Wfc = (const float*)d_in[5];
    const float* bfc = (const float*)d_in[6];
    const int*  eidx = (const int*)d_in[7];

    const int N = in_sizes[0] / IN_DIM;     // 100000
    const int E = in_sizes[7] / 2;          // 1600000
    const int* src = eidx;
    const int* dst = eidx + E;

    const int nScanBlocks = (N + SCAN_B - 1) / SCAN_B;

    // Workspace: cnt[N] | rowptr[N+1] | fillptr[N] | bsum[pad 1024] | dinv[N]
    //            | esrc[E] | bufA[N*64] | bufB[N*64]
    int*   cnt     = (int*)d_ws;
    int*   rowptr  = cnt + N;
    int*   fillptr = rowptr + (N + 1);
    int*   bsum    = fillptr + N;
    float* dinv    = (float*)(bsum + 1024);
    int*   esrc    = (int*)(dinv + N);
    float* bufA    = (float*)(esrc + E);
    float* bufB    = bufA + (size_t)N * HDIM;

    float* emb    = (float*)d_out;
    float* logits = emb + (size_t)N * HDIM;

    // ---- CSR build (shared by both conv layers) ----
    hipMemsetAsync(cnt, 0, (size_t)N * sizeof(int), stream);
    hist_kernel<<<(E + 255) / 256, 256, 0, stream>>>(dst, cnt, E);
    dinv_kernel<<<(N + 255) / 256, 256, 0, stream>>>(cnt, dinv, N);
    scan1_kernel<<<nScanBlocks, SCAN_B, 0, stream>>>(cnt, rowptr, bsum, N);
    scan2_kernel<<<1, SCAN_B, 0, stream>>>(bsum, nScanBlocks);
    scan3_kernel<<<nScanBlocks, SCAN_B, 0, stream>>>(rowptr, bsum, fillptr, N, E);
    fill_kernel<<<(E + 255) / 256, 256, 0, stream>>>(src, dst, fillptr, esrc, E);

    // ---- layer 1 ----
    gemm_kernel<IN_DIM, true, false><<<(N + 15) / 16, 256, 0, stream>>>(x, W1, nullptr, dinv, bufA, N);
    agg_kernel<true><<<(N + 3) / 4, 256, 0, stream>>>(bufA, esrc, rowptr, dinv, b1, bufB, N);

    // ---- layer 2 ----
    gemm_kernel<HDIM, true, false><<<(N + 15) / 16, 256, 0, stream>>>(bufB, W2, nullptr, dinv, bufA, N);
    agg_kernel<true><<<(N + 3) / 4, 256, 0, stream>>>(bufA, esrc, rowptr, dinv, b2, emb, N);

    // ---- FC head ----
    gemm_kernel<HDIM, false, true><<<(N + 15) / 16, 256, 0, stream>>>(emb, Wfc, bfc, nullptr, logits, N);
}

// Round 3
// 524.360 us; speedup vs baseline: 2.3363x; 1.3045x over previous
//
#include <hip/hip_runtime.h>

// FlexibleGCN forward on MI355X — Round 3: binned counting-sort CSR build
// (no global atomics, L2-resident scatter windows) + Round-2 gather pipeline.
//
//   Pass A: bucket = dst>>8 (391 buckets x 256 nodes)
//     A1: per-block LDS hist -> histg[bucket][block]
//     A2: per-bucket exclusive scan across blocks (-> per-(bucket,block) offs)
//     A3: exclusive scan of bucket totals -> bucketbase
//     A4: scatter (src,dst) into staging[bucket regions] via LDS cursors
//   Pass B: one block per bucket: local hist+scan -> rowptr, dinv, esrc
//   Then: gemm1 -> agg1 -> gemm2 -> agg2 -> gemmFC  (unchanged from R2)

constexpr int IN_DIM  = 128;
constexpr int HDIM    = 64;
constexpr int NBLK_A  = 256;   // blocks in pass A (must match histg stride)
constexpr int BSH     = 8;     // bucket shift: 256 nodes per bucket
constexpr int MAXNB   = 512;   // max buckets supported (N <= 131072)

// ---------- CSR build ----------

__global__ void binA_count(const int* __restrict__ dst, int* __restrict__ histg,
                           int E, int NB, int chunk) {
    __shared__ int h[MAXNB];
    for (int i = threadIdx.x; i < NB; i += 256) h[i] = 0;
    __syncthreads();
    int beg = blockIdx.x * chunk;
    int end = min(E, beg + chunk);
    for (int e = beg + threadIdx.x; e < end; e += 256)
        atomicAdd(&h[dst[e] >> BSH], 1);
    __syncthreads();
    for (int i = threadIdx.x; i < NB; i += 256)
        histg[i * NBLK_A + blockIdx.x] = h[i];
}

// One block per bucket: exclusive scan of histg[b][0..NBLK_A) in place; total -> btot[b].
__global__ void binA_scanblocks(int* __restrict__ histg, int* __restrict__ btot) {
    __shared__ int sm[NBLK_A];
    int tid = threadIdx.x;
    int v = histg[blockIdx.x * NBLK_A + tid];
    sm[tid] = v;
    __syncthreads();
    for (int off = 1; off < NBLK_A; off <<= 1) {
        int t = (tid >= off) ? sm[tid - off] : 0;
        __syncthreads();
        sm[tid] += t;
        __syncthreads();
    }
    histg[blockIdx.x * NBLK_A + tid] = sm[tid] - v;   // exclusive
    if (tid == NBLK_A - 1) btot[blockIdx.x] = sm[tid];
}

// Single block: exclusive scan of bucket totals -> bucketbase[0..NB], bucketbase[NB]=E.
__global__ void binA_scanbuckets(const int* __restrict__ btot, int* __restrict__ bucketbase,
                                 int NB) {
    __shared__ int sm[MAXNB];
    int tid = threadIdx.x;    // blockDim = MAXNB
    int v = (tid < NB) ? btot[tid] : 0;
    sm[tid] = v;
    __syncthreads();
    for (int off = 1; off < MAXNB; off <<= 1) {
        int t = (tid >= off) ? sm[tid - off] : 0;
        __syncthreads();
        sm[tid] += t;
        __syncthreads();
    }
    if (tid < NB) bucketbase[tid] = sm[tid] - v;
    if (tid == MAXNB - 1) bucketbase[NB] = sm[tid];   // == E
}

__global__ void binA_scatter(const int* __restrict__ src, const int* __restrict__ dst,
                             const int* __restrict__ histg, const int* __restrict__ bucketbase,
                             int2* __restrict__ staging, int E, int NB, int chunk) {
    __shared__ int cur[MAXNB];
    for (int i = threadIdx.x; i < NB; i += 256)
        cur[i] = bucketbase[i] + histg[i * NBLK_A + blockIdx.x];
    __syncthreads();
    int beg = blockIdx.x * chunk;
    int end = min(E, beg + chunk);
    for (int e = beg + threadIdx.x; e < end; e += 256) {
        int s = src[e];
        int d = dst[e];
        int pos = atomicAdd(&cur[d >> BSH], 1);
        staging[pos] = make_int2(s, d);
    }
}

// One block per bucket: local hist + scan -> rowptr/dinv; scatter esrc in a
// ~16KB L2-resident window.
__global__ void binB_finalize(const int2* __restrict__ staging, const int* __restrict__ bucketbase,
                              int* __restrict__ rowptr, int* __restrict__ esrc,
                              float* __restrict__ dinv, int N, int NB) {
    __shared__ int cnt[256], sm[256], cur[256];
    int tid = threadIdx.x;
    int b = blockIdx.x;
    int node0 = b << BSH;
    int nloc = min(256, N - node0);
    int ebeg = bucketbase[b], eend = bucketbase[b + 1];
    cnt[tid] = 0;
    __syncthreads();
    for (int e = ebeg + tid; e < eend; e += 256)
        atomicAdd(&cnt[staging[e].y & 255], 1);
    __syncthreads();
    int v = cnt[tid];
    sm[tid] = v;
    __syncthreads();
    for (int off = 1; off < 256; off <<= 1) {
        int t = (tid >= off) ? sm[tid - off] : 0;
        __syncthreads();
        sm[tid] += t;
        __syncthreads();
    }
    int excl = sm[tid] - v;
    cur[tid] = excl;
    __syncthreads();
    if (tid < nloc) {
        rowptr[node0 + tid] = ebeg + excl;
        dinv[node0 + tid] = rsqrtf((float)v + 1.0f);   // +1 self-loop
    }
    if (b == 0 && tid == 0) rowptr[N] = bucketbase[NB];
    for (int e = ebeg + tid; e < eend; e += 256) {
        int2 sd = staging[e];
        int pos = ebeg + atomicAdd(&cur[sd.y & 255], 1);
        esrc[pos] = sd.x;
    }
}

// ---------- dense layers (unchanged from R2) ----------

template<int K, bool SCALE, bool BIAS>
__global__ void gemm_kernel(const float* __restrict__ X, const float* __restrict__ W,
                            const float* __restrict__ bias, const float* __restrict__ dinv,
                            float* __restrict__ Y, int n) {
    __shared__ float Ws[K * 64];
    int tid = threadIdx.x;
    for (int i = tid; i < K * 64; i += 256) Ws[i] = W[i];
    __syncthreads();
    int j = tid & 63;
    int w = tid >> 6;
    int node0 = blockIdx.x * 16 + w * 4;
    if (node0 >= n) return;
    const float* x0 = X + (size_t)node0 * K;
    float acc0 = 0.f, acc1 = 0.f, acc2 = 0.f, acc3 = 0.f;
#pragma unroll 8
    for (int k = 0; k < K; ++k) {
        float wv = Ws[k * 64 + j];
        acc0 += x0[k]         * wv;
        acc1 += x0[K + k]     * wv;
        acc2 += x0[2 * K + k] * wv;
        acc3 += x0[3 * K + k] * wv;
    }
    float accs[4] = {acc0, acc1, acc2, acc3};
#pragma unroll
    for (int r = 0; r < 4; ++r) {
        int node = node0 + r;
        if (node < n) {
            float vv = accs[r];
            if (BIAS) vv += bias[j];
            if (SCALE) vv *= dinv[node];
            Y[(size_t)node * 64 + j] = vv;
        }
    }
}

template<bool RELU>
__global__ void agg_kernel(const float* __restrict__ hp, const int* __restrict__ esrc,
                           const int* __restrict__ rowptr, const float* __restrict__ dinv,
                           const float* __restrict__ bias, float* __restrict__ out, int n) {
    int node = blockIdx.x * 4 + (threadIdx.x >> 6);
    if (node >= n) return;
    int j = threadIdx.x & 63;
    int beg = rowptr[node], end = rowptr[node + 1];
    float acc = hp[(size_t)node * 64 + j];  // self-loop (hp already dinv[src]-scaled)
    int k = beg;
    for (; k + 4 <= end; k += 4) {
        int s0 = esrc[k], s1 = esrc[k + 1], s2 = esrc[k + 2], s3 = esrc[k + 3];
        float v0 = hp[(size_t)s0 * 64 + j];
        float v1 = hp[(size_t)s1 * 64 + j];
        float v2 = hp[(size_t)s2 * 64 + j];
        float v3 = hp[(size_t)s3 * 64 + j];
        acc += v0 + v1 + v2 + v3;
    }
    for (; k < end; ++k) acc += hp[(size_t)esrc[k] * 64 + j];
    float v = dinv[node] * acc + bias[j];
    out[(size_t)node * 64 + j] = RELU ? fmaxf(v, 0.f) : v;
}

extern "C" void kernel_launch(void* const* d_in, const int* in_sizes, int n_in,
                              void* d_out, int out_size, void* d_ws, size_t ws_size,
                              hipStream_t stream) {
    const float* x   = (const float*)d_in[0];
    const float* W1  = (const float*)d_in[1];
    const float* b1  = (const float*)d_in[2];
    const float* W2  = (const float*)d_in[3];
    const float* b2  = (const float*)d_in[4];
    const float* Wfc = (const float*)d_in[5];
    const float* bfc = (const float*)d_in[6];
    const int*  eidx = (const int*)d_in[7];

    const int N = in_sizes[0] / IN_DIM;     // 100000
    const int E = in_sizes[7] / 2;          // 1600000
    const int* src = eidx;
    const int* dst = eidx + E;

    const int NB    = (N + 255) >> BSH;     // 391 buckets
    const int chunk = (E + NBLK_A - 1) / NBLK_A;

    // ws layout (4B units, all even-sized for 8B alignment of staging):
    // rowptr[N+2] | dinv[N] | histg[NB*NBLK_A] | btot[512] | bucketbase[512]
    // | esrc[E] | bufA[N*64] (staging int2[E] aliases bufA) | bufB[N*64]
    int*   rowptr     = (int*)d_ws;
    float* dinv       = (float*)(rowptr + (N + 2));
    int*   histg      = (int*)(dinv + N);
    int*   btot       = histg + (size_t)NB * NBLK_A + (((size_t)NB * NBLK_A) & 1);
    int*   bucketbase = btot + 512;
    int*   esrc       = bucketbase + 512;
    float* bufA       = (float*)(esrc + E + (E & 1));
    float* bufB       = bufA + (size_t)N * HDIM;
    int2*  staging    = (int2*)bufA;

    float* emb    = (float*)d_out;
    float* logits = emb + (size_t)N * HDIM;

    // ---- CSR build (shared by both conv layers) ----
    binA_count<<<NBLK_A, 256, 0, stream>>>(dst, histg, E, NB, chunk);
    binA_scanblocks<<<NB, NBLK_A, 0, stream>>>(histg, btot);
    binA_scanbuckets<<<1, MAXNB, 0, stream>>>(btot, bucketbase, NB);
    binA_scatter<<<NBLK_A, 256, 0, stream>>>(src, dst, histg, bucketbase, staging, E, NB, chunk);
    binB_finalize<<<NB, 256, 0, stream>>>(staging, bucketbase, rowptr, esrc, dinv, N, NB);

    // ---- layer 1 ----
    gemm_kernel<IN_DIM, true, false><<<(N + 15) / 16, 256, 0, stream>>>(x, W1, nullptr, dinv, bufA, N);
    agg_kernel<true><<<(N + 3) / 4, 256, 0, stream>>>(bufA, esrc, rowptr, dinv, b1, bufB, N);

    // ---- layer 2 ----
    gemm_kernel<HDIM, true, false><<<(N + 15) / 16, 256, 0, stream>>>(bufB, W2, nullptr, dinv, bufA, N);
    agg_kernel<true><<<(N + 3) / 4, 256, 0, stream>>>(bufA, esrc, rowptr, dinv, b2, emb, N);

    // ---- FC head ----
    gemm_kernel<HDIM, false, true><<<(N + 15) / 16, 256, 0, stream>>>(emb, Wfc, bfc, nullptr, logits, N);
}

// Round 4
// 394.202 us; speedup vs baseline: 3.1077x; 1.3302x over previous
//
#include <hip/hip_runtime.h>

// FlexibleGCN forward on MI355X — Round 4: register-blocked vector GEMM
// (128x64 tile, 8x4 micro-tile/thread, K chunked by 32, X transposed in LDS).
// CSR build (binned counting sort) and gather-agg unchanged from Round 3.

constexpr int IN_DIM  = 128;
constexpr int HDIM    = 64;
constexpr int NBLK_A  = 256;   // blocks in pass A (must match histg stride)
constexpr int BSH     = 8;     // bucket shift: 256 nodes per bucket
constexpr int MAXNB   = 512;   // max buckets supported (N <= 131072)

// ---------- CSR build ----------

__global__ void binA_count(const int* __restrict__ dst, int* __restrict__ histg,
                           int E, int NB, int chunk) {
    __shared__ int h[MAXNB];
    for (int i = threadIdx.x; i < NB; i += 256) h[i] = 0;
    __syncthreads();
    int beg = blockIdx.x * chunk;
    int end = min(E, beg + chunk);
    for (int e = beg + threadIdx.x; e < end; e += 256)
        atomicAdd(&h[dst[e] >> BSH], 1);
    __syncthreads();
    for (int i = threadIdx.x; i < NB; i += 256)
        histg[i * NBLK_A + blockIdx.x] = h[i];
}

__global__ void binA_scanblocks(int* __restrict__ histg, int* __restrict__ btot) {
    __shared__ int sm[NBLK_A];
    int tid = threadIdx.x;
    int v = histg[blockIdx.x * NBLK_A + tid];
    sm[tid] = v;
    __syncthreads();
    for (int off = 1; off < NBLK_A; off <<= 1) {
        int t = (tid >= off) ? sm[tid - off] : 0;
        __syncthreads();
        sm[tid] += t;
        __syncthreads();
    }
    histg[blockIdx.x * NBLK_A + tid] = sm[tid] - v;   // exclusive
    if (tid == NBLK_A - 1) btot[blockIdx.x] = sm[tid];
}

__global__ void binA_scanbuckets(const int* __restrict__ btot, int* __restrict__ bucketbase,
                                 int NB) {
    __shared__ int sm[MAXNB];
    int tid = threadIdx.x;    // blockDim = MAXNB
    int v = (tid < NB) ? btot[tid] : 0;
    sm[tid] = v;
    __syncthreads();
    for (int off = 1; off < MAXNB; off <<= 1) {
        int t = (tid >= off) ? sm[tid - off] : 0;
        __syncthreads();
        sm[tid] += t;
        __syncthreads();
    }
    if (tid < NB) bucketbase[tid] = sm[tid] - v;
    if (tid == MAXNB - 1) bucketbase[NB] = sm[tid];   // == E
}

__global__ void binA_scatter(const int* __restrict__ src, const int* __restrict__ dst,
                             const int* __restrict__ histg, const int* __restrict__ bucketbase,
                             int2* __restrict__ staging, int E, int NB, int chunk) {
    __shared__ int cur[MAXNB];
    for (int i = threadIdx.x; i < NB; i += 256)
        cur[i] = bucketbase[i] + histg[i * NBLK_A + blockIdx.x];
    __syncthreads();
    int beg = blockIdx.x * chunk;
    int end = min(E, beg + chunk);
    for (int e = beg + threadIdx.x; e < end; e += 256) {
        int s = src[e];
        int d = dst[e];
        int pos = atomicAdd(&cur[d >> BSH], 1);
        staging[pos] = make_int2(s, d);
    }
}

__global__ void binB_finalize(const int2* __restrict__ staging, const int* __restrict__ bucketbase,
                              int* __restrict__ rowptr, int* __restrict__ esrc,
                              float* __restrict__ dinv, int N, int NB) {
    __shared__ int cnt[256], sm[256], cur[256];
    int tid = threadIdx.x;
    int b = blockIdx.x;
    int node0 = b << BSH;
    int nloc = min(256, N - node0);
    int ebeg = bucketbase[b], eend = bucketbase[b + 1];
    cnt[tid] = 0;
    __syncthreads();
    for (int e = ebeg + tid; e < eend; e += 256)
        atomicAdd(&cnt[staging[e].y & 255], 1);
    __syncthreads();
    int v = cnt[tid];
    sm[tid] = v;
    __syncthreads();
    for (int off = 1; off < 256; off <<= 1) {
        int t = (tid >= off) ? sm[tid - off] : 0;
        __syncthreads();
        sm[tid] += t;
        __syncthreads();
    }
    int excl = sm[tid] - v;
    cur[tid] = excl;
    __syncthreads();
    if (tid < nloc) {
        rowptr[node0 + tid] = ebeg + excl;
        dinv[node0 + tid] = rsqrtf((float)v + 1.0f);   // +1 self-loop
    }
    if (b == 0 && tid == 0) rowptr[N] = bucketbase[NB];
    for (int e = ebeg + tid; e < eend; e += 256) {
        int2 sd = staging[e];
        int pos = ebeg + atomicAdd(&cur[sd.y & 255], 1);
        esrc[pos] = sd.x;
    }
}

// ---------- dense layers ----------

// Y[n][64] = X[n][K] @ W[K][64]; optional *dinv[row], optional +bias.
// 256 threads, tile 128 rows x 64 cols; thread = 8 rows x 4 cols micro-tile.
// K chunked by KC=32; X chunk transposed in LDS (Xt[k][row], stride 132:
// multiple of 4 for b128 alignment, !=0 mod 32 so row-groups {0,8,16,24}
// land on distinct banks).
template<int K, bool SCALE, bool BIAS>
__global__ __launch_bounds__(256, 4) void gemm_kernel(
        const float* __restrict__ X, const float* __restrict__ W,
        const float* __restrict__ bias, const float* __restrict__ dinv,
        float* __restrict__ Y, int n) {
    constexpr int KC = 32;
    constexpr int XSTR = 132;                 // floats
    __shared__ float Xt[KC * XSTR];           // 16.9 KB
    __shared__ float Ws[KC * 64];             // 8 KB
    const int tid = threadIdx.x;
    const int node0 = blockIdx.x * 128;
    const int r0 = (tid >> 4) * 8;            // 0..120
    const int c0 = (tid & 15) * 4;            // 0..60

    float acc[8][4];
#pragma unroll
    for (int a = 0; a < 8; ++a)
#pragma unroll
        for (int b = 0; b < 4; ++b) acc[a][b] = 0.f;

    for (int kc = 0; kc < K; kc += KC) {
        __syncthreads();
        // stage X chunk transposed: 1024 float4 slots; slot s: row=s>>3, kq=s&7
#pragma unroll
        for (int i = 0; i < 4; ++i) {
            int s = tid + i * 256;
            int row = s >> 3;
            int kq = s & 7;
            int grow = node0 + row;
            float4 v = make_float4(0.f, 0.f, 0.f, 0.f);
            if (grow < n) v = *(const float4*)&X[(size_t)grow * K + kc + kq * 4];
            Xt[(kq * 4 + 0) * XSTR + row] = v.x;
            Xt[(kq * 4 + 1) * XSTR + row] = v.y;
            Xt[(kq * 4 + 2) * XSTR + row] = v.z;
            Xt[(kq * 4 + 3) * XSTR + row] = v.w;
        }
        // stage W chunk: KC x 64 floats = 512 float4; 2 per thread
#pragma unroll
        for (int i = 0; i < 2; ++i) {
            int s = tid + i * 256;
            *(float4*)&Ws[s * 4] = *(const float4*)&W[(size_t)kc * 64 + s * 4];
        }
        __syncthreads();
#pragma unroll
        for (int kk = 0; kk < KC; kk += 4) {
            float4 xa[4][2];
            float4 wv[4];
#pragma unroll
            for (int i = 0; i < 4; ++i) {
                xa[i][0] = *(const float4*)&Xt[(kk + i) * XSTR + r0];
                xa[i][1] = *(const float4*)&Xt[(kk + i) * XSTR + r0 + 4];
                wv[i]    = *(const float4*)&Ws[(kk + i) * 64 + c0];
            }
#pragma unroll
            for (int i = 0; i < 4; ++i) {
                const float* xp = (const float*)&xa[i][0];
                const float* wp = (const float*)&wv[i];
#pragma unroll
                for (int rr = 0; rr < 8; ++rr)
#pragma unroll
                    for (int cc = 0; cc < 4; ++cc)
                        acc[rr][cc] += xp[rr] * wp[cc];
            }
        }
    }
#pragma unroll
    for (int rr = 0; rr < 8; ++rr) {
        int node = node0 + r0 + rr;
        if (node < n) {
            float4 v;
            float* vp = (float*)&v;
#pragma unroll
            for (int cc = 0; cc < 4; ++cc) {
                float t = acc[rr][cc];
                if (BIAS) t += bias[c0 + cc];
                vp[cc] = t;
            }
            if (SCALE) {
                float d = dinv[node];
                v.x *= d; v.y *= d; v.z *= d; v.w *= d;
            }
            *(float4*)&Y[(size_t)node * 64 + c0] = v;
        }
    }
}

// One wave per node: acc[j] = hp[node][j] + sum_{s in N(node)} hp[s][j]
template<bool RELU>
__global__ void agg_kernel(const float* __restrict__ hp, const int* __restrict__ esrc,
                           const int* __restrict__ rowptr, const float* __restrict__ dinv,
                           const float* __restrict__ bias, float* __restrict__ out, int n) {
    int node = blockIdx.x * 4 + (threadIdx.x >> 6);
    if (node >= n) return;
    int j = threadIdx.x & 63;
    int beg = rowptr[node], end = rowptr[node + 1];
    float acc = hp[(size_t)node * 64 + j];  // self-loop (hp already dinv[src]-scaled)
    int k = beg;
    for (; k + 4 <= end; k += 4) {
        int s0 = esrc[k], s1 = esrc[k + 1], s2 = esrc[k + 2], s3 = esrc[k + 3];
        float v0 = hp[(size_t)s0 * 64 + j];
        float v1 = hp[(size_t)s1 * 64 + j];
        float v2 = hp[(size_t)s2 * 64 + j];
        float v3 = hp[(size_t)s3 * 64 + j];
        acc += v0 + v1 + v2 + v3;
    }
    for (; k < end; ++k) acc += hp[(size_t)esrc[k] * 64 + j];
    float v = dinv[node] * acc + bias[j];
    out[(size_t)node * 64 + j] = RELU ? fmaxf(v, 0.f) : v;
}

extern "C" void kernel_launch(void* const* d_in, const int* in_sizes, int n_in,
                              void* d_out, int out_size, void* d_ws, size_t ws_size,
                              hipStream_t stream) {
    const float* x   = (const float*)d_in[0];
    const float* W1  = (const float*)d_in[1];
    const float* b1  = (const float*)d_in[2];
    const float* W2  = (const float*)d_in[3];
    const float* b2  = (const float*)d_in[4];
    const float* Wfc = (const float*)d_in[5];
    const float* bfc = (const float*)d_in[6];
    const int*  eidx = (const int*)d_in[7];

    const int N = in_sizes[0] / IN_DIM;     // 100000
    const int E = in_sizes[7] / 2;          // 1600000
    const int* src = eidx;
    const int* dst = eidx + E;

    const int NB    = (N + 255) >> BSH;     // 391 buckets
    const int chunk = (E + NBLK_A - 1) / NBLK_A;

    // ws layout: rowptr[N+2] | dinv[N] | histg[NB*NBLK_A] | btot[512]
    //            | bucketbase[512] | esrc[E] | bufA[N*64] (aliases staging) | bufB[N*64]
    int*   rowptr     = (int*)d_ws;
    float* dinv       = (float*)(rowptr + (N + 2));
    int*   histg      = (int*)(dinv + N);
    int*   btot       = histg + (size_t)NB * NBLK_A + (((size_t)NB * NBLK_A) & 1);
    int*   bucketbase = btot + 512;
    int*   esrc       = bucketbase + 512;
    float* bufA       = (float*)(esrc + E + (E & 1));
    float* bufB       = bufA + (size_t)N * HDIM;
    int2*  staging    = (int2*)bufA;

    float* emb    = (float*)d_out;
    float* logits = emb + (size_t)N * HDIM;

    // ---- CSR build (shared by both conv layers) ----
    binA_count<<<NBLK_A, 256, 0, stream>>>(dst, histg, E, NB, chunk);
    binA_scanblocks<<<NB, NBLK_A, 0, stream>>>(histg, btot);
    binA_scanbuckets<<<1, MAXNB, 0, stream>>>(btot, bucketbase, NB);
    binA_scatter<<<NBLK_A, 256, 0, stream>>>(src, dst, histg, bucketbase, staging, E, NB, chunk);
    binB_finalize<<<NB, 256, 0, stream>>>(staging, bucketbase, rowptr, esrc, dinv, N, NB);

    const int gBlocks = (N + 127) / 128;

    // ---- layer 1 ----
    gemm_kernel<IN_DIM, true, false><<<gBlocks, 256, 0, stream>>>(x, W1, nullptr, dinv, bufA, N);
    agg_kernel<true><<<(N + 3) / 4, 256, 0, stream>>>(bufA, esrc, rowptr, dinv, b1, bufB, N);

    // ---- layer 2 ----
    gemm_kernel<HDIM, true, false><<<gBlocks, 256, 0, stream>>>(bufB, W2, nullptr, dinv, bufA, N);
    agg_kernel<true><<<(N + 3) / 4, 256, 0, stream>>>(bufA, esrc, rowptr, dinv, b2, emb, N);

    // ---- FC head ----
    gemm_kernel<HDIM, false, true><<<gBlocks, 256, 0, stream>>>(emb, Wfc, bfc, nullptr, logits, N);
}

// Round 5
// 352.881 us; speedup vs baseline: 3.4716x; 1.1171x over previous
//
#include <hip/hip_runtime.h>
#include <hip/hip_bf16.h>

// FlexibleGCN forward on MI355X — Round 5:
//  * hp (dinv .* X@W intermediates) stored as bf16 -> gather bytes halved
//    (agg was FETCH-bound at 271 MB/dispatch; 25.6 MB table >> 4 MB/XCD L2)
//  * CSR staging packed to one int: (src<<8)|(dst&255)  (src < 2^17)
// CSR build + register-blocked GEMM structure otherwise as Round 4.

constexpr int IN_DIM  = 128;
constexpr int HDIM    = 64;
constexpr int NBLK_A  = 256;   // blocks in pass A (must match histg stride)
constexpr int BSH     = 8;     // bucket shift: 256 nodes per bucket
constexpr int MAXNB   = 512;   // max buckets supported (N <= 131072)

// ---------- CSR build ----------

__global__ void binA_count(const int* __restrict__ dst, int* __restrict__ histg,
                           int E, int NB, int chunk) {
    __shared__ int h[MAXNB];
    for (int i = threadIdx.x; i < NB; i += 256) h[i] = 0;
    __syncthreads();
    int beg = blockIdx.x * chunk;
    int end = min(E, beg + chunk);
    for (int e = beg + threadIdx.x; e < end; e += 256)
        atomicAdd(&h[dst[e] >> BSH], 1);
    __syncthreads();
    for (int i = threadIdx.x; i < NB; i += 256)
        histg[i * NBLK_A + blockIdx.x] = h[i];
}

__global__ void binA_scanblocks(int* __restrict__ histg, int* __restrict__ btot) {
    __shared__ int sm[NBLK_A];
    int tid = threadIdx.x;
    int v = histg[blockIdx.x * NBLK_A + tid];
    sm[tid] = v;
    __syncthreads();
    for (int off = 1; off < NBLK_A; off <<= 1) {
        int t = (tid >= off) ? sm[tid - off] : 0;
        __syncthreads();
        sm[tid] += t;
        __syncthreads();
    }
    histg[blockIdx.x * NBLK_A + tid] = sm[tid] - v;   // exclusive
    if (tid == NBLK_A - 1) btot[blockIdx.x] = sm[tid];
}

__global__ void binA_scanbuckets(const int* __restrict__ btot, int* __restrict__ bucketbase,
                                 int NB) {
    __shared__ int sm[MAXNB];
    int tid = threadIdx.x;    // blockDim = MAXNB
    int v = (tid < NB) ? btot[tid] : 0;
    sm[tid] = v;
    __syncthreads();
    for (int off = 1; off < MAXNB; off <<= 1) {
        int t = (tid >= off) ? sm[tid - off] : 0;
        __syncthreads();
        sm[tid] += t;
        __syncthreads();
    }
    if (tid < NB) bucketbase[tid] = sm[tid] - v;
    if (tid == MAXNB - 1) bucketbase[NB] = sm[tid];   // == E
}

__global__ void binA_scatter(const int* __restrict__ src, const int* __restrict__ dst,
                             const int* __restrict__ histg, const int* __restrict__ bucketbase,
                             int* __restrict__ staging, int E, int NB, int chunk) {
    __shared__ int cur[MAXNB];
    for (int i = threadIdx.x; i < NB; i += 256)
        cur[i] = bucketbase[i] + histg[i * NBLK_A + blockIdx.x];
    __syncthreads();
    int beg = blockIdx.x * chunk;
    int end = min(E, beg + chunk);
    for (int e = beg + threadIdx.x; e < end; e += 256) {
        int s = src[e];
        int d = dst[e];
        int pos = atomicAdd(&cur[d >> BSH], 1);
        staging[pos] = (s << BSH) | (d & 255);    // src<2^17, local dst 8 bits
    }
}

__global__ void binB_finalize(const int* __restrict__ staging, const int* __restrict__ bucketbase,
                              int* __restrict__ rowptr, int* __restrict__ esrc,
                              float* __restrict__ dinv, int N, int NB) {
    __shared__ int cnt[256], sm[256], cur[256];
    int tid = threadIdx.x;
    int b = blockIdx.x;
    int node0 = b << BSH;
    int nloc = min(256, N - node0);
    int ebeg = bucketbase[b], eend = bucketbase[b + 1];
    cnt[tid] = 0;
    __syncthreads();
    for (int e = ebeg + tid; e < eend; e += 256)
        atomicAdd(&cnt[staging[e] & 255], 1);
    __syncthreads();
    int v = cnt[tid];
    sm[tid] = v;
    __syncthreads();
    for (int off = 1; off < 256; off <<= 1) {
        int t = (tid >= off) ? sm[tid - off] : 0;
        __syncthreads();
        sm[tid] += t;
        __syncthreads();
    }
    int excl = sm[tid] - v;
    cur[tid] = excl;
    __syncthreads();
    if (tid < nloc) {
        rowptr[node0 + tid] = ebeg + excl;
        dinv[node0 + tid] = rsqrtf((float)v + 1.0f);   // +1 self-loop
    }
    if (b == 0 && tid == 0) rowptr[N] = bucketbase[NB];
    for (int e = ebeg + tid; e < eend; e += 256) {
        int p = staging[e];
        int pos = ebeg + atomicAdd(&cur[p & 255], 1);
        esrc[pos] = p >> BSH;
    }
}

// ---------- dense layers ----------

// Y[n][64] = X[n][K] @ W[K][64]; optional *dinv[row], optional +bias.
// 256 threads, tile 128 rows x 64 cols; thread = 8x4 micro-tile; KC=32.
// OBF16: round-store output as bf16 (for the gather-bound agg).
template<int K, bool SCALE, bool BIAS, bool OBF16>
__global__ __launch_bounds__(256, 4) void gemm_kernel(
        const float* __restrict__ X, const float* __restrict__ W,
        const float* __restrict__ bias, const float* __restrict__ dinv,
        void* __restrict__ Yv, int n) {
    constexpr int KC = 32;
    constexpr int XSTR = 132;                 // floats
    __shared__ float Xt[KC * XSTR];           // 16.9 KB
    __shared__ float Ws[KC * 64];             // 8 KB
    const int tid = threadIdx.x;
    const int node0 = blockIdx.x * 128;
    const int r0 = (tid >> 4) * 8;            // 0..120
    const int c0 = (tid & 15) * 4;            // 0..60

    float acc[8][4];
#pragma unroll
    for (int a = 0; a < 8; ++a)
#pragma unroll
        for (int b = 0; b < 4; ++b) acc[a][b] = 0.f;

    for (int kc = 0; kc < K; kc += KC) {
        __syncthreads();
#pragma unroll
        for (int i = 0; i < 4; ++i) {
            int s = tid + i * 256;
            int row = s >> 3;
            int kq = s & 7;
            int grow = node0 + row;
            float4 v = make_float4(0.f, 0.f, 0.f, 0.f);
            if (grow < n) v = *(const float4*)&X[(size_t)grow * K + kc + kq * 4];
            Xt[(kq * 4 + 0) * XSTR + row] = v.x;
            Xt[(kq * 4 + 1) * XSTR + row] = v.y;
            Xt[(kq * 4 + 2) * XSTR + row] = v.z;
            Xt[(kq * 4 + 3) * XSTR + row] = v.w;
        }
#pragma unroll
        for (int i = 0; i < 2; ++i) {
            int s = tid + i * 256;
            *(float4*)&Ws[s * 4] = *(const float4*)&W[(size_t)kc * 64 + s * 4];
        }
        __syncthreads();
#pragma unroll
        for (int kk = 0; kk < KC; kk += 4) {
            float4 xa[4][2];
            float4 wv[4];
#pragma unroll
            for (int i = 0; i < 4; ++i) {
                xa[i][0] = *(const float4*)&Xt[(kk + i) * XSTR + r0];
                xa[i][1] = *(const float4*)&Xt[(kk + i) * XSTR + r0 + 4];
                wv[i]    = *(const float4*)&Ws[(kk + i) * 64 + c0];
            }
#pragma unroll
            for (int i = 0; i < 4; ++i) {
                const float* xp = (const float*)&xa[i][0];
                const float* wp = (const float*)&wv[i];
#pragma unroll
                for (int rr = 0; rr < 8; ++rr)
#pragma unroll
                    for (int cc = 0; cc < 4; ++cc)
                        acc[rr][cc] += xp[rr] * wp[cc];
            }
        }
    }
#pragma unroll
    for (int rr = 0; rr < 8; ++rr) {
        int node = node0 + r0 + rr;
        if (node < n) {
            float d = SCALE ? dinv[node] : 1.0f;
            float t[4];
#pragma unroll
            for (int cc = 0; cc < 4; ++cc) {
                float v = acc[rr][cc];
                if (BIAS) v += bias[c0 + cc];
                t[cc] = v * d;
            }
            if (OBF16) {
                __hip_bfloat16 vb[4];
#pragma unroll
                for (int cc = 0; cc < 4; ++cc) vb[cc] = __float2bfloat16(t[cc]);
                *(uint2*)&((__hip_bfloat16*)Yv)[(size_t)node * 64 + c0] = *(uint2*)vb;
            } else {
                *(float4*)&((float*)Yv)[(size_t)node * 64 + c0] = *(float4*)t;
            }
        }
    }
}

// One wave per node: acc[j] = hp[node][j] + sum_{s in N(node)} hp[s][j]
// hp is bf16 (dinv[src]-prescaled); accumulate fp32.
template<bool RELU>
__global__ void agg_kernel(const __hip_bfloat16* __restrict__ hp, const int* __restrict__ esrc,
                           const int* __restrict__ rowptr, const float* __restrict__ dinv,
                           const float* __restrict__ bias, float* __restrict__ out, int n) {
    int node = blockIdx.x * 4 + (threadIdx.x >> 6);
    if (node >= n) return;
    int j = threadIdx.x & 63;
    int beg = rowptr[node], end = rowptr[node + 1];
    float acc = __bfloat162float(hp[(size_t)node * 64 + j]);  // self-loop
    int k = beg;
    for (; k + 4 <= end; k += 4) {
        int s0 = esrc[k], s1 = esrc[k + 1], s2 = esrc[k + 2], s3 = esrc[k + 3];
        float v0 = __bfloat162float(hp[(size_t)s0 * 64 + j]);
        float v1 = __bfloat162float(hp[(size_t)s1 * 64 + j]);
        float v2 = __bfloat162float(hp[(size_t)s2 * 64 + j]);
        float v3 = __bfloat162float(hp[(size_t)s3 * 64 + j]);
        acc += v0 + v1 + v2 + v3;
    }
    for (; k < end; ++k) acc += __bfloat162float(hp[(size_t)esrc[k] * 64 + j]);
    float v = dinv[node] * acc + bias[j];
    out[(size_t)node * 64 + j] = RELU ? fmaxf(v, 0.f) : v;
}

extern "C" void kernel_launch(void* const* d_in, const int* in_sizes, int n_in,
                              void* d_out, int out_size, void* d_ws, size_t ws_size,
                              hipStream_t stream) {
    const float* x   = (const float*)d_in[0];
    const float* W1  = (const float*)d_in[1];
    const float* b1  = (const float*)d_in[2];
    const float* W2  = (const float*)d_in[3];
    const float* b2  = (const float*)d_in[4];
    const float* Wfc = (const float*)d_in[5];
    const float* bfc = (const float*)d_in[6];
    const int*  eidx = (const int*)d_in[7];

    const int N = in_sizes[0] / IN_DIM;     // 100000
    const int E = in_sizes[7] / 2;          // 1600000
    const int* src = eidx;
    const int* dst = eidx + E;

    const int NB    = (N + 255) >> BSH;     // 391 buckets
    const int chunk = (E + NBLK_A - 1) / NBLK_A;

    // ws layout (4B units): rowptr[N+2] | dinv[N] | histg[NB*NBLK_A] | btot[512]
    //   | bucketbase[512] | esrc[E] | bufA[N*64 floats] | bufB[N*64 floats]
    // staging int[E] and hp (bf16, N*64*2B) both alias bufA (disjoint lifetimes).
    int*   rowptr     = (int*)d_ws;
    float* dinv       = (float*)(rowptr + (N + 2));
    int*   histg      = (int*)(dinv + N);
    int*   btot       = histg + (size_t)NB * NBLK_A + (((size_t)NB * NBLK_A) & 1);
    int*   bucketbase = btot + 512;
    int*   esrc       = bucketbase + 512;
    float* bufA       = (float*)(esrc + E + (E & 1));
    float* bufB       = bufA + (size_t)N * HDIM;
    int*   staging    = (int*)bufA;
    __hip_bfloat16* hp = (__hip_bfloat16*)bufA;

    float* emb    = (float*)d_out;
    float* logits = emb + (size_t)N * HDIM;

    // ---- CSR build (shared by both conv layers) ----
    binA_count<<<NBLK_A, 256, 0, stream>>>(dst, histg, E, NB, chunk);
    binA_scanblocks<<<NB, NBLK_A, 0, stream>>>(histg, btot);
    binA_scanbuckets<<<1, MAXNB, 0, stream>>>(btot, bucketbase, NB);
    binA_scatter<<<NBLK_A, 256, 0, stream>>>(src, dst, histg, bucketbase, staging, E, NB, chunk);
    binB_finalize<<<NB, 256, 0, stream>>>(staging, bucketbase, rowptr, esrc, dinv, N, NB);

    const int gBlocks = (N + 127) / 128;

    // ---- layer 1 ----  hp1 (bf16) aliases staging: staging dead after binB.
    gemm_kernel<IN_DIM, true, false, true><<<gBlocks, 256, 0, stream>>>(x, W1, nullptr, dinv, hp, N);
    agg_kernel<true><<<(N + 3) / 4, 256, 0, stream>>>(hp, esrc, rowptr, dinv, b1, bufB, N);

    // ---- layer 2 ----
    gemm_kernel<HDIM, true, false, true><<<gBlocks, 256, 0, stream>>>(bufB, W2, nullptr, dinv, hp, N);
    agg_kernel<true><<<(N + 3) / 4, 256, 0, stream>>>(hp, esrc, rowptr, dinv, b2, emb, N);

    // ---- FC head ----
    gemm_kernel<HDIM, false, true, false><<<gBlocks, 256, 0, stream>>>(emb, Wfc, bfc, nullptr, logits, N);
}

// Round 6
// 328.657 us; speedup vs baseline: 3.7275x; 1.0737x over previous
//
#include <hip/hip_runtime.h>
#include <hip/hip_bf16.h>

// FlexibleGCN forward on MI355X — Round 6:
//  * agg_kernel: 8-deep batched gathers + predicated tail batch (latency-bound
//    fix; R5 showed 2.67 TB/s @ 33% peak, unroll-4 + serialized tail).
//  * Rest identical to Round 5 (bf16 hp, packed CSR staging, reg-blocked GEMM).

constexpr int IN_DIM  = 128;
constexpr int HDIM    = 64;
constexpr int NBLK_A  = 256;   // blocks in pass A (must match histg stride)
constexpr int BSH     = 8;     // bucket shift: 256 nodes per bucket
constexpr int MAXNB   = 512;   // max buckets supported (N <= 131072)

// ---------- CSR build ----------

__global__ void binA_count(const int* __restrict__ dst, int* __restrict__ histg,
                           int E, int NB, int chunk) {
    __shared__ int h[MAXNB];
    for (int i = threadIdx.x; i < NB; i += 256) h[i] = 0;
    __syncthreads();
    int beg = blockIdx.x * chunk;
    int end = min(E, beg + chunk);
    for (int e = beg + threadIdx.x; e < end; e += 256)
        atomicAdd(&h[dst[e] >> BSH], 1);
    __syncthreads();
    for (int i = threadIdx.x; i < NB; i += 256)
        histg[i * NBLK_A + blockIdx.x] = h[i];
}

__global__ void binA_scanblocks(int* __restrict__ histg, int* __restrict__ btot) {
    __shared__ int sm[NBLK_A];
    int tid = threadIdx.x;
    int v = histg[blockIdx.x * NBLK_A + tid];
    sm[tid] = v;
    __syncthreads();
    for (int off = 1; off < NBLK_A; off <<= 1) {
        int t = (tid >= off) ? sm[tid - off] : 0;
        __syncthreads();
        sm[tid] += t;
        __syncthreads();
    }
    histg[blockIdx.x * NBLK_A + tid] = sm[tid] - v;   // exclusive
    if (tid == NBLK_A - 1) btot[blockIdx.x] = sm[tid];
}

__global__ void binA_scanbuckets(const int* __restrict__ btot, int* __restrict__ bucketbase,
                                 int NB) {
    __shared__ int sm[MAXNB];
    int tid = threadIdx.x;    // blockDim = MAXNB
    int v = (tid < NB) ? btot[tid] : 0;
    sm[tid] = v;
    __syncthreads();
    for (int off = 1; off < MAXNB; off <<= 1) {
        int t = (tid >= off) ? sm[tid - off] : 0;
        __syncthreads();
        sm[tid] += t;
        __syncthreads();
    }
    if (tid < NB) bucketbase[tid] = sm[tid] - v;
    if (tid == MAXNB - 1) bucketbase[NB] = sm[tid];   // == E
}

__global__ void binA_scatter(const int* __restrict__ src, const int* __restrict__ dst,
                             const int* __restrict__ histg, const int* __restrict__ bucketbase,
                             int* __restrict__ staging, int E, int NB, int chunk) {
    __shared__ int cur[MAXNB];
    for (int i = threadIdx.x; i < NB; i += 256)
        cur[i] = bucketbase[i] + histg[i * NBLK_A + blockIdx.x];
    __syncthreads();
    int beg = blockIdx.x * chunk;
    int end = min(E, beg + chunk);
    for (int e = beg + threadIdx.x; e < end; e += 256) {
        int s = src[e];
        int d = dst[e];
        int pos = atomicAdd(&cur[d >> BSH], 1);
        staging[pos] = (s << BSH) | (d & 255);    // src<2^17, local dst 8 bits
    }
}

__global__ void binB_finalize(const int* __restrict__ staging, const int* __restrict__ bucketbase,
                              int* __restrict__ rowptr, int* __restrict__ esrc,
                              float* __restrict__ dinv, int N, int NB) {
    __shared__ int cnt[256], sm[256], cur[256];
    int tid = threadIdx.x;
    int b = blockIdx.x;
    int node0 = b << BSH;
    int nloc = min(256, N - node0);
    int ebeg = bucketbase[b], eend = bucketbase[b + 1];
    cnt[tid] = 0;
    __syncthreads();
    for (int e = ebeg + tid; e < eend; e += 256)
        atomicAdd(&cnt[staging[e] & 255], 1);
    __syncthreads();
    int v = cnt[tid];
    sm[tid] = v;
    __syncthreads();
    for (int off = 1; off < 256; off <<= 1) {
        int t = (tid >= off) ? sm[tid - off] : 0;
        __syncthreads();
        sm[tid] += t;
        __syncthreads();
    }
    int excl = sm[tid] - v;
    cur[tid] = excl;
    __syncthreads();
    if (tid < nloc) {
        rowptr[node0 + tid] = ebeg + excl;
        dinv[node0 + tid] = rsqrtf((float)v + 1.0f);   // +1 self-loop
    }
    if (b == 0 && tid == 0) rowptr[N] = bucketbase[NB];
    for (int e = ebeg + tid; e < eend; e += 256) {
        int p = staging[e];
        int pos = ebeg + atomicAdd(&cur[p & 255], 1);
        esrc[pos] = p >> BSH;
    }
}

// ---------- dense layers ----------

// Y[n][64] = X[n][K] @ W[K][64]; optional *dinv[row], optional +bias.
// 256 threads, tile 128 rows x 64 cols; thread = 8x4 micro-tile; KC=32.
template<int K, bool SCALE, bool BIAS, bool OBF16>
__global__ __launch_bounds__(256, 4) void gemm_kernel(
        const float* __restrict__ X, const float* __restrict__ W,
        const float* __restrict__ bias, const float* __restrict__ dinv,
        void* __restrict__ Yv, int n) {
    constexpr int KC = 32;
    constexpr int XSTR = 132;                 // floats
    __shared__ float Xt[KC * XSTR];           // 16.9 KB
    __shared__ float Ws[KC * 64];             // 8 KB
    const int tid = threadIdx.x;
    const int node0 = blockIdx.x * 128;
    const int r0 = (tid >> 4) * 8;            // 0..120
    const int c0 = (tid & 15) * 4;            // 0..60

    float acc[8][4];
#pragma unroll
    for (int a = 0; a < 8; ++a)
#pragma unroll
        for (int b = 0; b < 4; ++b) acc[a][b] = 0.f;

    for (int kc = 0; kc < K; kc += KC) {
        __syncthreads();
#pragma unroll
        for (int i = 0; i < 4; ++i) {
            int s = tid + i * 256;
            int row = s >> 3;
            int kq = s & 7;
            int grow = node0 + row;
            float4 v = make_float4(0.f, 0.f, 0.f, 0.f);
            if (grow < n) v = *(const float4*)&X[(size_t)grow * K + kc + kq * 4];
            Xt[(kq * 4 + 0) * XSTR + row] = v.x;
            Xt[(kq * 4 + 1) * XSTR + row] = v.y;
            Xt[(kq * 4 + 2) * XSTR + row] = v.z;
            Xt[(kq * 4 + 3) * XSTR + row] = v.w;
        }
#pragma unroll
        for (int i = 0; i < 2; ++i) {
            int s = tid + i * 256;
            *(float4*)&Ws[s * 4] = *(const float4*)&W[(size_t)kc * 64 + s * 4];
        }
        __syncthreads();
#pragma unroll
        for (int kk = 0; kk < KC; kk += 4) {
            float4 xa[4][2];
            float4 wv[4];
#pragma unroll
            for (int i = 0; i < 4; ++i) {
                xa[i][0] = *(const float4*)&Xt[(kk + i) * XSTR + r0];
                xa[i][1] = *(const float4*)&Xt[(kk + i) * XSTR + r0 + 4];
                wv[i]    = *(const float4*)&Ws[(kk + i) * 64 + c0];
            }
#pragma unroll
            for (int i = 0; i < 4; ++i) {
                const float* xp = (const float*)&xa[i][0];
                const float* wp = (const float*)&wv[i];
#pragma unroll
                for (int rr = 0; rr < 8; ++rr)
#pragma unroll
                    for (int cc = 0; cc < 4; ++cc)
                        acc[rr][cc] += xp[rr] * wp[cc];
            }
        }
    }
#pragma unroll
    for (int rr = 0; rr < 8; ++rr) {
        int node = node0 + r0 + rr;
        if (node < n) {
            float d = SCALE ? dinv[node] : 1.0f;
            float t[4];
#pragma unroll
            for (int cc = 0; cc < 4; ++cc) {
                float v = acc[rr][cc];
                if (BIAS) v += bias[c0 + cc];
                t[cc] = v * d;
            }
            if (OBF16) {
                __hip_bfloat16 vb[4];
#pragma unroll
                for (int cc = 0; cc < 4; ++cc) vb[cc] = __float2bfloat16(t[cc]);
                *(uint2*)&((__hip_bfloat16*)Yv)[(size_t)node * 64 + c0] = *(uint2*)vb;
            } else {
                *(float4*)&((float*)Yv)[(size_t)node * 64 + c0] = *(float4*)t;
            }
        }
    }
}

// One wave per node; lane j = feature j. 8-deep batched gathers; tail is one
// predicated batch of 8 (clamped index re-reads the L1-hot self row, masked
// out of the sum) so no load ever waits on a previous load.
template<bool RELU>
__global__ __launch_bounds__(256) void agg_kernel(
        const __hip_bfloat16* __restrict__ hp, const int* __restrict__ esrc,
        const int* __restrict__ rowptr, const float* __restrict__ dinv,
        const float* __restrict__ bias, float* __restrict__ out, int n) {
    int node = blockIdx.x * 4 + (threadIdx.x >> 6);
    if (node >= n) return;
    int j = threadIdx.x & 63;
    const __hip_bfloat16* hpj = hp + j;
    int beg = rowptr[node], end = rowptr[node + 1];
    float acc = __bfloat162float(hpj[(size_t)node * 64]);  // self-loop
    int k = beg;
    for (; k + 8 <= end; k += 8) {
        int s[8];
#pragma unroll
        for (int i = 0; i < 8; ++i) s[i] = esrc[k + i];
        float v[8];
#pragma unroll
        for (int i = 0; i < 8; ++i) v[i] = __bfloat162float(hpj[(size_t)s[i] * 64]);
        acc += ((v[0] + v[1]) + (v[2] + v[3])) + ((v[4] + v[5]) + (v[6] + v[7]));
    }
    if (k < end) {  // 1..7 remaining: one predicated batch
        int s[8];
#pragma unroll
        for (int i = 0; i < 8; ++i) s[i] = esrc[min(k + i, end - 1)];
        float v[8];
#pragma unroll
        for (int i = 0; i < 8; ++i) v[i] = __bfloat162float(hpj[(size_t)s[i] * 64]);
        float t = 0.f;
#pragma unroll
        for (int i = 0; i < 8; ++i) t += (k + i < end) ? v[i] : 0.f;
        acc += t;
    }
    float v = dinv[node] * acc + bias[j];
    out[(size_t)node * 64 + j] = RELU ? fmaxf(v, 0.f) : v;
}

extern "C" void kernel_launch(void* const* d_in, const int* in_sizes, int n_in,
                              void* d_out, int out_size, void* d_ws, size_t ws_size,
                              hipStream_t stream) {
    const float* x   = (const float*)d_in[0];
    const float* W1  = (const float*)d_in[1];
    const float* b1  = (const float*)d_in[2];
    const float* W2  = (const float*)d_in[3];
    const float* b2  = (const float*)d_in[4];
    const float* Wfc = (const float*)d_in[5];
    const float* bfc = (const float*)d_in[6];
    const int*  eidx = (const int*)d_in[7];

    const int N = in_sizes[0] / IN_DIM;     // 100000
    const int E = in_sizes[7] / 2;          // 1600000
    const int* src = eidx;
    const int* dst = eidx + E;

    const int NB    = (N + 255) >> BSH;     // 391 buckets
    const int chunk = (E + NBLK_A - 1) / NBLK_A;

    // ws layout (4B units): rowptr[N+2] | dinv[N] | histg[NB*NBLK_A] | btot[512]
    //   | bucketbase[512] | esrc[E] | bufA[N*64 floats] | bufB[N*64 floats]
    // staging int[E] and hp (bf16, N*64*2B) both alias bufA (disjoint lifetimes).
    int*   rowptr     = (int*)d_ws;
    float* dinv       = (float*)(rowptr + (N + 2));
    int*   histg      = (int*)(dinv + N);
    int*   btot       = histg + (size_t)NB * NBLK_A + (((size_t)NB * NBLK_A) & 1);
    int*   bucketbase = btot + 512;
    int*   esrc       = bucketbase + 512;
    float* bufA       = (float*)(esrc + E + (E & 1));
    float* bufB       = bufA + (size_t)N * HDIM;
    int*   staging    = (int*)bufA;
    __hip_bfloat16* hp = (__hip_bfloat16*)bufA;

    float* emb    = (float*)d_out;
    float* logits = emb + (size_t)N * HDIM;

    // ---- CSR build (shared by both conv layers) ----
    binA_count<<<NBLK_A, 256, 0, stream>>>(dst, histg, E, NB, chunk);
    binA_scanblocks<<<NB, NBLK_A, 0, stream>>>(histg, btot);
    binA_scanbuckets<<<1, MAXNB, 0, stream>>>(btot, bucketbase, NB);
    binA_scatter<<<NBLK_A, 256, 0, stream>>>(src, dst, histg, bucketbase, staging, E, NB, chunk);
    binB_finalize<<<NB, 256, 0, stream>>>(staging, bucketbase, rowptr, esrc, dinv, N, NB);

    const int gBlocks = (N + 127) / 128;

    // ---- layer 1 ----  hp1 (bf16) aliases staging: staging dead after binB.
    gemm_kernel<IN_DIM, true, false, true><<<gBlocks, 256, 0, stream>>>(x, W1, nullptr, dinv, hp, N);
    agg_kernel<true><<<(N + 3) / 4, 256, 0, stream>>>(hp, esrc, rowptr, dinv, b1, bufB, N);

    // ---- layer 2 ----
    gemm_kernel<HDIM, true, false, true><<<gBlocks, 256, 0, stream>>>(bufB, W2, nullptr, dinv, hp, N);
    agg_kernel<true><<<(N + 3) / 4, 256, 0, stream>>>(hp, esrc, rowptr, dinv, b2, emb, N);

    // ---- FC head ----
    gemm_kernel<HDIM, false, true, false><<<gBlocks, 256, 0, stream>>>(emb, Wfc, bfc, nullptr, logits, N);
}

// Round 7
// 319.677 us; speedup vs baseline: 3.8322x; 1.0281x over previous
//
#include <hip/hip_runtime.h>
#include <hip/hip_bf16.h>

// FlexibleGCN forward on MI355X — Round 7:
//  * agg: 16-deep gather batches (probe queue-depth vs DRAM-efficiency limit)
//  * distinct kernel names per stage (profiler attribution of the ~215us tier)
//  * h1 stored bf16 (agg1 out, gemm2 in): -25 MB streaming traffic
// CSR build unchanged from Round 5/6.

constexpr int IN_DIM  = 128;
constexpr int HDIM    = 64;
constexpr int NBLK_A  = 256;   // blocks in pass A (must match histg stride)
constexpr int BSH     = 8;     // bucket shift: 256 nodes per bucket
constexpr int MAXNB   = 512;   // max buckets supported (N <= 131072)

__device__ __forceinline__ float bf2f(unsigned short u) {
    return __uint_as_float(((unsigned int)u) << 16);
}

// ---------- CSR build ----------

__global__ void binA_count(const int* __restrict__ dst, int* __restrict__ histg,
                           int E, int NB, int chunk) {
    __shared__ int h[MAXNB];
    for (int i = threadIdx.x; i < NB; i += 256) h[i] = 0;
    __syncthreads();
    int beg = blockIdx.x * chunk;
    int end = min(E, beg + chunk);
    for (int e = beg + threadIdx.x; e < end; e += 256)
        atomicAdd(&h[dst[e] >> BSH], 1);
    __syncthreads();
    for (int i = threadIdx.x; i < NB; i += 256)
        histg[i * NBLK_A + blockIdx.x] = h[i];
}

__global__ void binA_scanblocks(int* __restrict__ histg, int* __restrict__ btot) {
    __shared__ int sm[NBLK_A];
    int tid = threadIdx.x;
    int v = histg[blockIdx.x * NBLK_A + tid];
    sm[tid] = v;
    __syncthreads();
    for (int off = 1; off < NBLK_A; off <<= 1) {
        int t = (tid >= off) ? sm[tid - off] : 0;
        __syncthreads();
        sm[tid] += t;
        __syncthreads();
    }
    histg[blockIdx.x * NBLK_A + tid] = sm[tid] - v;   // exclusive
    if (tid == NBLK_A - 1) btot[blockIdx.x] = sm[tid];
}

__global__ void binA_scanbuckets(const int* __restrict__ btot, int* __restrict__ bucketbase,
                                 int NB) {
    __shared__ int sm[MAXNB];
    int tid = threadIdx.x;    // blockDim = MAXNB
    int v = (tid < NB) ? btot[tid] : 0;
    sm[tid] = v;
    __syncthreads();
    for (int off = 1; off < MAXNB; off <<= 1) {
        int t = (tid >= off) ? sm[tid - off] : 0;
        __syncthreads();
        sm[tid] += t;
        __syncthreads();
    }
    if (tid < NB) bucketbase[tid] = sm[tid] - v;
    if (tid == MAXNB - 1) bucketbase[NB] = sm[tid];   // == E
}

__global__ void binA_scatter(const int* __restrict__ src, const int* __restrict__ dst,
                             const int* __restrict__ histg, const int* __restrict__ bucketbase,
                             int* __restrict__ staging, int E, int NB, int chunk) {
    __shared__ int cur[MAXNB];
    for (int i = threadIdx.x; i < NB; i += 256)
        cur[i] = bucketbase[i] + histg[i * NBLK_A + blockIdx.x];
    __syncthreads();
    int beg = blockIdx.x * chunk;
    int end = min(E, beg + chunk);
    for (int e = beg + threadIdx.x; e < end; e += 256) {
        int s = src[e];
        int d = dst[e];
        int pos = atomicAdd(&cur[d >> BSH], 1);
        staging[pos] = (s << BSH) | (d & 255);    // src<2^17, local dst 8 bits
    }
}

__global__ void binB_finalize(const int* __restrict__ staging, const int* __restrict__ bucketbase,
                              int* __restrict__ rowptr, int* __restrict__ esrc,
                              float* __restrict__ dinv, int N, int NB) {
    __shared__ int cnt[256], sm[256], cur[256];
    int tid = threadIdx.x;
    int b = blockIdx.x;
    int node0 = b << BSH;
    int nloc = min(256, N - node0);
    int ebeg = bucketbase[b], eend = bucketbase[b + 1];
    cnt[tid] = 0;
    __syncthreads();
    for (int e = ebeg + tid; e < eend; e += 256)
        atomicAdd(&cnt[staging[e] & 255], 1);
    __syncthreads();
    int v = cnt[tid];
    sm[tid] = v;
    __syncthreads();
    for (int off = 1; off < 256; off <<= 1) {
        int t = (tid >= off) ? sm[tid - off] : 0;
        __syncthreads();
        sm[tid] += t;
        __syncthreads();
    }
    int excl = sm[tid] - v;
    cur[tid] = excl;
    __syncthreads();
    if (tid < nloc) {
        rowptr[node0 + tid] = ebeg + excl;
        dinv[node0 + tid] = rsqrtf((float)v + 1.0f);   // +1 self-loop
    }
    if (b == 0 && tid == 0) rowptr[N] = bucketbase[NB];
    for (int e = ebeg + tid; e < eend; e += 256) {
        int p = staging[e];
        int pos = ebeg + atomicAdd(&cur[p & 255], 1);
        esrc[pos] = p >> BSH;
    }
}

// ---------- dense layers ----------

// Y[n][64] = X[n][K] @ W[K][64]; optional *dinv[row], optional +bias.
// 256 threads, tile 128 rows x 64 cols; thread = 8x4 micro-tile; KC=32.
// IBF16: X is bf16; OBF16: Y stored bf16.
template<int K, bool IBF16, bool SCALE, bool BIAS, bool OBF16>
__device__ __forceinline__ void gemm_body(
        const void* __restrict__ Xv, const float* __restrict__ W,
        const float* __restrict__ bias, const float* __restrict__ dinv,
        void* __restrict__ Yv, int n) {
    constexpr int KC = 32;
    constexpr int XSTR = 132;                 // floats
    __shared__ float Xt[KC * XSTR];           // 16.9 KB
    __shared__ float Ws[KC * 64];             // 8 KB
    const int tid = threadIdx.x;
    const int node0 = blockIdx.x * 128;
    const int r0 = (tid >> 4) * 8;            // 0..120
    const int c0 = (tid & 15) * 4;            // 0..60

    float acc[8][4];
#pragma unroll
    for (int a = 0; a < 8; ++a)
#pragma unroll
        for (int b = 0; b < 4; ++b) acc[a][b] = 0.f;

    for (int kc = 0; kc < K; kc += KC) {
        __syncthreads();
#pragma unroll
        for (int i = 0; i < 4; ++i) {
            int s = tid + i * 256;
            int row = s >> 3;
            int kq = s & 7;
            int grow = node0 + row;
            float4 v = make_float4(0.f, 0.f, 0.f, 0.f);
            if (grow < n) {
                if (IBF16) {
                    uint2 u = *(const uint2*)&((const unsigned short*)Xv)[(size_t)grow * K + kc + kq * 4];
                    v.x = bf2f(u.x & 0xffff); v.y = bf2f(u.x >> 16);
                    v.z = bf2f(u.y & 0xffff); v.w = bf2f(u.y >> 16);
                } else {
                    v = *(const float4*)&((const float*)Xv)[(size_t)grow * K + kc + kq * 4];
                }
            }
            Xt[(kq * 4 + 0) * XSTR + row] = v.x;
            Xt[(kq * 4 + 1) * XSTR + row] = v.y;
            Xt[(kq * 4 + 2) * XSTR + row] = v.z;
            Xt[(kq * 4 + 3) * XSTR + row] = v.w;
        }
#pragma unroll
        for (int i = 0; i < 2; ++i) {
            int s = tid + i * 256;
            *(float4*)&Ws[s * 4] = *(const float4*)&W[(size_t)kc * 64 + s * 4];
        }
        __syncthreads();
#pragma unroll
        for (int kk = 0; kk < KC; kk += 4) {
            float4 xa[4][2];
            float4 wv[4];
#pragma unroll
            for (int i = 0; i < 4; ++i) {
                xa[i][0] = *(const float4*)&Xt[(kk + i) * XSTR + r0];
                xa[i][1] = *(const float4*)&Xt[(kk + i) * XSTR + r0 + 4];
                wv[i]    = *(const float4*)&Ws[(kk + i) * 64 + c0];
            }
#pragma unroll
            for (int i = 0; i < 4; ++i) {
                const float* xp = (const float*)&xa[i][0];
                const float* wp = (const float*)&wv[i];
#pragma unroll
                for (int rr = 0; rr < 8; ++rr)
#pragma unroll
                    for (int cc = 0; cc < 4; ++cc)
                        acc[rr][cc] += xp[rr] * wp[cc];
            }
        }
    }
#pragma unroll
    for (int rr = 0; rr < 8; ++rr) {
        int node = node0 + r0 + rr;
        if (node < n) {
            float d = SCALE ? dinv[node] : 1.0f;
            float t[4];
#pragma unroll
            for (int cc = 0; cc < 4; ++cc) {
                float v = acc[rr][cc];
                if (BIAS) v += bias[c0 + cc];
                t[cc] = v * d;
            }
            if (OBF16) {
                __hip_bfloat16 vb[4];
#pragma unroll
                for (int cc = 0; cc < 4; ++cc) vb[cc] = __float2bfloat16(t[cc]);
                *(uint2*)&((__hip_bfloat16*)Yv)[(size_t)node * 64 + c0] = *(uint2*)vb;
            } else {
                *(float4*)&((float*)Yv)[(size_t)node * 64 + c0] = *(float4*)t;
            }
        }
    }
}

__global__ __launch_bounds__(256, 4) void gemm1_kernel(
        const float* X, const float* W, const float* dinv, void* Y, int n) {
    gemm_body<IN_DIM, false, true, false, true>(X, W, nullptr, dinv, Y, n);
}
__global__ __launch_bounds__(256, 4) void gemm2_kernel(
        const void* X, const float* W, const float* dinv, void* Y, int n) {
    gemm_body<HDIM, true, true, false, true>(X, W, nullptr, dinv, Y, n);
}
__global__ __launch_bounds__(256, 4) void fc_kernel(
        const float* X, const float* W, const float* bias, void* Y, int n) {
    gemm_body<HDIM, false, false, true, false>(X, W, bias, nullptr, Y, n);
}

// One wave per node; lane j = feature j. 16-deep batched gathers; tail is one
// predicated batch of 16 (clamped index re-reads an L1-hot row, masked out).
// out = relu(dinv[node]*acc + bias[j]) stored as OutT (bf16 or fp32).
template<bool OBF16>
__device__ __forceinline__ void agg_body(
        const unsigned short* __restrict__ hp, const int* __restrict__ esrc,
        const int* __restrict__ rowptr, const float* __restrict__ dinv,
        const float* __restrict__ bias, void* __restrict__ out, int n) {
    int node = blockIdx.x * 4 + (threadIdx.x >> 6);
    if (node >= n) return;
    int j = threadIdx.x & 63;
    const unsigned short* hpj = hp + j;
    int beg = rowptr[node], end = rowptr[node + 1];
    float acc = bf2f(hpj[(size_t)node * 64]);  // self-loop
    int k = beg;
    for (; k + 16 <= end; k += 16) {
        int s[16];
#pragma unroll
        for (int i = 0; i < 16; ++i) s[i] = esrc[k + i];
        float v[16];
#pragma unroll
        for (int i = 0; i < 16; ++i) v[i] = bf2f(hpj[(size_t)s[i] * 64]);
        float t0 = ((v[0] + v[1]) + (v[2] + v[3])) + ((v[4] + v[5]) + (v[6] + v[7]));
        float t1 = ((v[8] + v[9]) + (v[10] + v[11])) + ((v[12] + v[13]) + (v[14] + v[15]));
        acc += t0 + t1;
    }
    if (k < end) {  // 1..15 remaining: one predicated batch
        int s[16];
#pragma unroll
        for (int i = 0; i < 16; ++i) s[i] = esrc[min(k + i, end - 1)];
        float v[16];
#pragma unroll
        for (int i = 0; i < 16; ++i) v[i] = bf2f(hpj[(size_t)s[i] * 64]);
        float t = 0.f;
#pragma unroll
        for (int i = 0; i < 16; ++i) t += (k + i < end) ? v[i] : 0.f;
        acc += t;
    }
    float v = fmaxf(dinv[node] * acc + bias[j], 0.f);
    if (OBF16) {
        ((__hip_bfloat16*)out)[(size_t)node * 64 + j] = __float2bfloat16(v);
    } else {
        ((float*)out)[(size_t)node * 64 + j] = v;
    }
}

__global__ __launch_bounds__(256) void agg1_kernel(
        const unsigned short* hp, const int* esrc, const int* rowptr,
        const float* dinv, const float* bias, void* out, int n) {
    agg_body<true>(hp, esrc, rowptr, dinv, bias, out, n);
}
__global__ __launch_bounds__(256) void agg2_kernel(
        const unsigned short* hp, const int* esrc, const int* rowptr,
        const float* dinv, const float* bias, void* out, int n) {
    agg_body<false>(hp, esrc, rowptr, dinv, bias, out, n);
}

extern "C" void kernel_launch(void* const* d_in, const int* in_sizes, int n_in,
                              void* d_out, int out_size, void* d_ws, size_t ws_size,
                              hipStream_t stream) {
    const float* x   = (const float*)d_in[0];
    const float* W1  = (const float*)d_in[1];
    const float* b1  = (const float*)d_in[2];
    const float* W2  = (const float*)d_in[3];
    const float* b2  = (const float*)d_in[4];
    const float* Wfc = (const float*)d_in[5];
    const float* bfc = (const float*)d_in[6];
    const int*  eidx = (const int*)d_in[7];

    const int N = in_sizes[0] / IN_DIM;     // 100000
    const int E = in_sizes[7] / 2;          // 1600000
    const int* src = eidx;
    const int* dst = eidx + E;

    const int NB    = (N + 255) >> BSH;     // 391 buckets
    const int chunk = (E + NBLK_A - 1) / NBLK_A;

    // ws layout (4B units): rowptr[N+2] | dinv[N] | histg[NB*NBLK_A] | btot[512]
    //   | bucketbase[512] | esrc[E] | bufA[N*64 floats] | bufB[N*64 floats]
    // staging int[E] and hp1/hp2 (bf16) alias bufA; h1 (bf16) aliases bufB.
    int*   rowptr     = (int*)d_ws;
    float* dinv       = (float*)(rowptr + (N + 2));
    int*   histg      = (int*)(dinv + N);
    int*   btot       = histg + (size_t)NB * NBLK_A + (((size_t)NB * NBLK_A) & 1);
    int*   bucketbase = btot + 512;
    int*   esrc       = bucketbase + 512;
    float* bufA       = (float*)(esrc + E + (E & 1));
    float* bufB       = bufA + (size_t)N * HDIM;
    int*   staging    = (int*)bufA;
    unsigned short* hp = (unsigned short*)bufA;   // bf16 bits
    unsigned short* h1 = (unsigned short*)bufB;   // bf16 bits

    float* emb    = (float*)d_out;
    float* logits = emb + (size_t)N * HDIM;

    // ---- CSR build (shared by both conv layers) ----
    binA_count<<<NBLK_A, 256, 0, stream>>>(dst, histg, E, NB, chunk);
    binA_scanblocks<<<NB, NBLK_A, 0, stream>>>(histg, btot);
    binA_scanbuckets<<<1, MAXNB, 0, stream>>>(btot, bucketbase, NB);
    binA_scatter<<<NBLK_A, 256, 0, stream>>>(src, dst, histg, bucketbase, staging, E, NB, chunk);
    binB_finalize<<<NB, 256, 0, stream>>>(staging, bucketbase, rowptr, esrc, dinv, N, NB);

    const int gBlocks = (N + 127) / 128;
    const int aBlocks = (N + 3) / 4;

    // ---- layer 1 ----  hp1 (bf16) aliases staging: staging dead after binB.
    gemm1_kernel<<<gBlocks, 256, 0, stream>>>(x, W1, dinv, hp, N);
    agg1_kernel<<<aBlocks, 256, 0, stream>>>(hp, esrc, rowptr, dinv, b1, h1, N);

    // ---- layer 2 ----
    gemm2_kernel<<<gBlocks, 256, 0, stream>>>(h1, W2, dinv, hp, N);
    agg2_kernel<<<aBlocks, 256, 0, stream>>>(hp, esrc, rowptr, dinv, b2, emb, N);

    // ---- FC head ----
    fc_kernel<<<gBlocks, 256, 0, stream>>>(emb, Wfc, bfc, logits, N);
}

// Round 8
// 315.787 us; speedup vs baseline: 3.8794x; 1.0123x over previous
//
#include <hip/hip_runtime.h>
#include <hip/hip_bf16.h>

// FlexibleGCN forward on MI355X — Round 8:
//  * agg: 2 edges/wave (32 lanes x uint = 2 bf16 features each), depth-8
//    batches -> 16 edges in flight at R6's register cost. Cross-half
//    __shfl_xor(32) combine. (R7's 16-deep regressed: VGPR 40, occ 52%.)
//  * Rest identical to Round 7 (bf16 hp & h1, packed CSR staging, split names).

constexpr int IN_DIM  = 128;
constexpr int HDIM    = 64;
constexpr int NBLK_A  = 256;   // blocks in pass A (must match histg stride)
constexpr int BSH     = 8;     // bucket shift: 256 nodes per bucket
constexpr int MAXNB   = 512;   // max buckets supported (N <= 131072)

__device__ __forceinline__ float bf2f(unsigned int u) {
    return __uint_as_float(u << 16);
}
__device__ __forceinline__ unsigned short f2bf_bits(float f) {
    __hip_bfloat16 b = __float2bfloat16(f);
    return *(unsigned short*)&b;
}

// ---------- CSR build ----------

__global__ void binA_count(const int* __restrict__ dst, int* __restrict__ histg,
                           int E, int NB, int chunk) {
    __shared__ int h[MAXNB];
    for (int i = threadIdx.x; i < NB; i += 256) h[i] = 0;
    __syncthreads();
    int beg = blockIdx.x * chunk;
    int end = min(E, beg + chunk);
    for (int e = beg + threadIdx.x; e < end; e += 256)
        atomicAdd(&h[dst[e] >> BSH], 1);
    __syncthreads();
    for (int i = threadIdx.x; i < NB; i += 256)
        histg[i * NBLK_A + blockIdx.x] = h[i];
}

__global__ void binA_scanblocks(int* __restrict__ histg, int* __restrict__ btot) {
    __shared__ int sm[NBLK_A];
    int tid = threadIdx.x;
    int v = histg[blockIdx.x * NBLK_A + tid];
    sm[tid] = v;
    __syncthreads();
    for (int off = 1; off < NBLK_A; off <<= 1) {
        int t = (tid >= off) ? sm[tid - off] : 0;
        __syncthreads();
        sm[tid] += t;
        __syncthreads();
    }
    histg[blockIdx.x * NBLK_A + tid] = sm[tid] - v;   // exclusive
    if (tid == NBLK_A - 1) btot[blockIdx.x] = sm[tid];
}

__global__ void binA_scanbuckets(const int* __restrict__ btot, int* __restrict__ bucketbase,
                                 int NB) {
    __shared__ int sm[MAXNB];
    int tid = threadIdx.x;    // blockDim = MAXNB
    int v = (tid < NB) ? btot[tid] : 0;
    sm[tid] = v;
    __syncthreads();
    for (int off = 1; off < MAXNB; off <<= 1) {
        int t = (tid >= off) ? sm[tid - off] : 0;
        __syncthreads();
        sm[tid] += t;
        __syncthreads();
    }
    if (tid < NB) bucketbase[tid] = sm[tid] - v;
    if (tid == MAXNB - 1) bucketbase[NB] = sm[tid];   // == E
}

__global__ void binA_scatter(const int* __restrict__ src, const int* __restrict__ dst,
                             const int* __restrict__ histg, const int* __restrict__ bucketbase,
                             int* __restrict__ staging, int E, int NB, int chunk) {
    __shared__ int cur[MAXNB];
    for (int i = threadIdx.x; i < NB; i += 256)
        cur[i] = bucketbase[i] + histg[i * NBLK_A + blockIdx.x];
    __syncthreads();
    int beg = blockIdx.x * chunk;
    int end = min(E, beg + chunk);
    for (int e = beg + threadIdx.x; e < end; e += 256) {
        int s = src[e];
        int d = dst[e];
        int pos = atomicAdd(&cur[d >> BSH], 1);
        staging[pos] = (s << BSH) | (d & 255);    // src<2^17, local dst 8 bits
    }
}

__global__ void binB_finalize(const int* __restrict__ staging, const int* __restrict__ bucketbase,
                              int* __restrict__ rowptr, int* __restrict__ esrc,
                              float* __restrict__ dinv, int N, int NB) {
    __shared__ int cnt[256], sm[256], cur[256];
    int tid = threadIdx.x;
    int b = blockIdx.x;
    int node0 = b << BSH;
    int nloc = min(256, N - node0);
    int ebeg = bucketbase[b], eend = bucketbase[b + 1];
    cnt[tid] = 0;
    __syncthreads();
    for (int e = ebeg + tid; e < eend; e += 256)
        atomicAdd(&cnt[staging[e] & 255], 1);
    __syncthreads();
    int v = cnt[tid];
    sm[tid] = v;
    __syncthreads();
    for (int off = 1; off < 256; off <<= 1) {
        int t = (tid >= off) ? sm[tid - off] : 0;
        __syncthreads();
        sm[tid] += t;
        __syncthreads();
    }
    int excl = sm[tid] - v;
    cur[tid] = excl;
    __syncthreads();
    if (tid < nloc) {
        rowptr[node0 + tid] = ebeg + excl;
        dinv[node0 + tid] = rsqrtf((float)v + 1.0f);   // +1 self-loop
    }
    if (b == 0 && tid == 0) rowptr[N] = bucketbase[NB];
    for (int e = ebeg + tid; e < eend; e += 256) {
        int p = staging[e];
        int pos = ebeg + atomicAdd(&cur[p & 255], 1);
        esrc[pos] = p >> BSH;
    }
}

// ---------- dense layers ----------

// Y[n][64] = X[n][K] @ W[K][64]; optional *dinv[row], optional +bias.
// 256 threads, tile 128 rows x 64 cols; thread = 8x4 micro-tile; KC=32.
template<int K, bool IBF16, bool SCALE, bool BIAS, bool OBF16>
__device__ __forceinline__ void gemm_body(
        const void* __restrict__ Xv, const float* __restrict__ W,
        const float* __restrict__ bias, const float* __restrict__ dinv,
        void* __restrict__ Yv, int n) {
    constexpr int KC = 32;
    constexpr int XSTR = 132;                 // floats
    __shared__ float Xt[KC * XSTR];           // 16.9 KB
    __shared__ float Ws[KC * 64];             // 8 KB
    const int tid = threadIdx.x;
    const int node0 = blockIdx.x * 128;
    const int r0 = (tid >> 4) * 8;            // 0..120
    const int c0 = (tid & 15) * 4;            // 0..60

    float acc[8][4];
#pragma unroll
    for (int a = 0; a < 8; ++a)
#pragma unroll
        for (int b = 0; b < 4; ++b) acc[a][b] = 0.f;

    for (int kc = 0; kc < K; kc += KC) {
        __syncthreads();
#pragma unroll
        for (int i = 0; i < 4; ++i) {
            int s = tid + i * 256;
            int row = s >> 3;
            int kq = s & 7;
            int grow = node0 + row;
            float4 v = make_float4(0.f, 0.f, 0.f, 0.f);
            if (grow < n) {
                if (IBF16) {
                    uint2 u = *(const uint2*)&((const unsigned short*)Xv)[(size_t)grow * K + kc + kq * 4];
                    v.x = bf2f(u.x & 0xffff); v.y = bf2f(u.x >> 16);
                    v.z = bf2f(u.y & 0xffff); v.w = bf2f(u.y >> 16);
                } else {
                    v = *(const float4*)&((const float*)Xv)[(size_t)grow * K + kc + kq * 4];
                }
            }
            Xt[(kq * 4 + 0) * XSTR + row] = v.x;
            Xt[(kq * 4 + 1) * XSTR + row] = v.y;
            Xt[(kq * 4 + 2) * XSTR + row] = v.z;
            Xt[(kq * 4 + 3) * XSTR + row] = v.w;
        }
#pragma unroll
        for (int i = 0; i < 2; ++i) {
            int s = tid + i * 256;
            *(float4*)&Ws[s * 4] = *(const float4*)&W[(size_t)kc * 64 + s * 4];
        }
        __syncthreads();
#pragma unroll
        for (int kk = 0; kk < KC; kk += 4) {
            float4 xa[4][2];
            float4 wv[4];
#pragma unroll
            for (int i = 0; i < 4; ++i) {
                xa[i][0] = *(const float4*)&Xt[(kk + i) * XSTR + r0];
                xa[i][1] = *(const float4*)&Xt[(kk + i) * XSTR + r0 + 4];
                wv[i]    = *(const float4*)&Ws[(kk + i) * 64 + c0];
            }
#pragma unroll
            for (int i = 0; i < 4; ++i) {
                const float* xp = (const float*)&xa[i][0];
                const float* wp = (const float*)&wv[i];
#pragma unroll
                for (int rr = 0; rr < 8; ++rr)
#pragma unroll
                    for (int cc = 0; cc < 4; ++cc)
                        acc[rr][cc] += xp[rr] * wp[cc];
            }
        }
    }
#pragma unroll
    for (int rr = 0; rr < 8; ++rr) {
        int node = node0 + r0 + rr;
        if (node < n) {
            float d = SCALE ? dinv[node] : 1.0f;
            float t[4];
#pragma unroll
            for (int cc = 0; cc < 4; ++cc) {
                float v = acc[rr][cc];
                if (BIAS) v += bias[c0 + cc];
                t[cc] = v * d;
            }
            if (OBF16) {
                __hip_bfloat16 vb[4];
#pragma unroll
                for (int cc = 0; cc < 4; ++cc) vb[cc] = __float2bfloat16(t[cc]);
                *(uint2*)&((__hip_bfloat16*)Yv)[(size_t)node * 64 + c0] = *(uint2*)vb;
            } else {
                *(float4*)&((float*)Yv)[(size_t)node * 64 + c0] = *(float4*)t;
            }
        }
    }
}

__global__ __launch_bounds__(256, 4) void gemm1_kernel(
        const float* X, const float* W, const float* dinv, void* Y, int n) {
    gemm_body<IN_DIM, false, true, false, true>(X, W, nullptr, dinv, Y, n);
}
__global__ __launch_bounds__(256, 4) void gemm2_kernel(
        const void* X, const float* W, const float* dinv, void* Y, int n) {
    gemm_body<HDIM, true, true, false, true>(X, W, nullptr, dinv, Y, n);
}
__global__ __launch_bounds__(256, 4) void fc_kernel(
        const float* X, const float* W, const float* bias, void* Y, int n) {
    gemm_body<HDIM, false, false, true, false>(X, W, bias, nullptr, Y, n);
}

// One wave per node, 2 edges per wave: half-wave h (32 lanes) takes edges
// k+2i+h; lane l holds packed features {2l, 2l+1} as one uint (2 bf16).
// Depth-8 batches -> 16 edges in flight. Cross-half shfl_xor(32) combine.
template<bool OBF16>
__device__ __forceinline__ void agg_body(
        const unsigned short* __restrict__ hp, const int* __restrict__ esrc,
        const int* __restrict__ rowptr, const float* __restrict__ dinv,
        const float* __restrict__ bias, void* __restrict__ out, int n) {
    int node = blockIdx.x * 4 + (threadIdx.x >> 6);
    if (node >= n) return;
    int lane = threadIdx.x & 63;
    int half = lane >> 5;
    int l = lane & 31;
    const unsigned int* hp32 = (const unsigned int*)hp;   // row s -> hp32[s*32 + l]
    int beg = rowptr[node], end = rowptr[node + 1];

    float ax = 0.f, ay = 0.f;
    {   // self-loop, counted by half 0 only
        unsigned int u = hp32[(size_t)node * 32 + l];
        if (half == 0) { ax = bf2f(u & 0xffff); ay = bf2f(u >> 16); }
    }
    int k = beg;
    for (; k + 16 <= end; k += 16) {
        int s[8];
#pragma unroll
        for (int i = 0; i < 8; ++i) s[i] = esrc[k + 2 * i + half];
        unsigned int u[8];
#pragma unroll
        for (int i = 0; i < 8; ++i) u[i] = hp32[(size_t)s[i] * 32 + l];
        float vx[8], vy[8];
#pragma unroll
        for (int i = 0; i < 8; ++i) { vx[i] = bf2f(u[i] & 0xffff); vy[i] = bf2f(u[i] >> 16); }
        ax += ((vx[0] + vx[1]) + (vx[2] + vx[3])) + ((vx[4] + vx[5]) + (vx[6] + vx[7]));
        ay += ((vy[0] + vy[1]) + (vy[2] + vy[3])) + ((vy[4] + vy[5]) + (vy[6] + vy[7]));
    }
    if (k < end) {  // 1..15 remaining: one predicated depth-8 batch (16 slots)
        int s[8];
#pragma unroll
        for (int i = 0; i < 8; ++i) s[i] = esrc[min(k + 2 * i + half, end - 1)];
        unsigned int u[8];
#pragma unroll
        for (int i = 0; i < 8; ++i) u[i] = hp32[(size_t)s[i] * 32 + l];
        float tx = 0.f, ty = 0.f;
#pragma unroll
        for (int i = 0; i < 8; ++i) {
            bool m = (k + 2 * i + half) < end;
            tx += m ? bf2f(u[i] & 0xffff) : 0.f;
            ty += m ? bf2f(u[i] >> 16)    : 0.f;
        }
        ax += tx; ay += ty;
    }
    // combine halves (both halves end with the full sum)
    ax += __shfl_xor(ax, 32, 64);
    ay += __shfl_xor(ay, 32, 64);

    if (half == 0) {
        float d = dinv[node];
        float ox = fmaxf(d * ax + bias[2 * l], 0.f);
        float oy = fmaxf(d * ay + bias[2 * l + 1], 0.f);
        if (OBF16) {
            unsigned int packed = (unsigned int)f2bf_bits(ox) | ((unsigned int)f2bf_bits(oy) << 16);
            ((unsigned int*)out)[(size_t)node * 32 + l] = packed;
        } else {
            float2 o = make_float2(ox, oy);
            ((float2*)out)[(size_t)node * 32 + l] = o;
        }
    }
}

__global__ __launch_bounds__(256) void agg1_kernel(
        const unsigned short* hp, const int* esrc, const int* rowptr,
        const float* dinv, const float* bias, void* out, int n) {
    agg_body<true>(hp, esrc, rowptr, dinv, bias, out, n);
}
__global__ __launch_bounds__(256) void agg2_kernel(
        const unsigned short* hp, const int* esrc, const int* rowptr,
        const float* dinv, const float* bias, void* out, int n) {
    agg_body<false>(hp, esrc, rowptr, dinv, bias, out, n);
}

extern "C" void kernel_launch(void* const* d_in, const int* in_sizes, int n_in,
                              void* d_out, int out_size, void* d_ws, size_t ws_size,
                              hipStream_t stream) {
    const float* x   = (const float*)d_in[0];
    const float* W1  = (const float*)d_in[1];
    const float* b1  = (const float*)d_in[2];
    const float* W2  = (const float*)d_in[3];
    const float* b2  = (const float*)d_in[4];
    const float* Wfc = (const float*)d_in[5];
    const float* bfc = (const float*)d_in[6];
    const int*  eidx = (const int*)d_in[7];

    const int N = in_sizes[0] / IN_DIM;     // 100000
    const int E = in_sizes[7] / 2;          // 1600000
    const int* src = eidx;
    const int* dst = eidx + E;

    const int NB    = (N + 255) >> BSH;     // 391 buckets
    const int chunk = (E + NBLK_A - 1) / NBLK_A;

    // ws layout (4B units): rowptr[N+2] | dinv[N] | histg[NB*NBLK_A] | btot[512]
    //   | bucketbase[512] | esrc[E] | bufA[N*64 floats] | bufB[N*64 floats]
    // staging int[E] and hp (bf16) alias bufA; h1 (bf16) aliases bufB.
    int*   rowptr     = (int*)d_ws;
    float* dinv       = (float*)(rowptr + (N + 2));
    int*   histg      = (int*)(dinv + N);
    int*   btot       = histg + (size_t)NB * NBLK_A + (((size_t)NB * NBLK_A) & 1);
    int*   bucketbase = btot + 512;
    int*   esrc       = bucketbase + 512;
    float* bufA       = (float*)(esrc + E + (E & 1));
    float* bufB       = bufA + (size_t)N * HDIM;
    int*   staging    = (int*)bufA;
    unsigned short* hp = (unsigned short*)bufA;   // bf16 bits
    unsigned short* h1 = (unsigned short*)bufB;   // bf16 bits

    float* emb    = (float*)d_out;
    float* logits = emb + (size_t)N * HDIM;

    // ---- CSR build (shared by both conv layers) ----
    binA_count<<<NBLK_A, 256, 0, stream>>>(dst, histg, E, NB, chunk);
    binA_scanblocks<<<NB, NBLK_A, 0, stream>>>(histg, btot);
    binA_scanbuckets<<<1, MAXNB, 0, stream>>>(btot, bucketbase, NB);
    binA_scatter<<<NBLK_A, 256, 0, stream>>>(src, dst, histg, bucketbase, staging, E, NB, chunk);
    binB_finalize<<<NB, 256, 0, stream>>>(staging, bucketbase, rowptr, esrc, dinv, N, NB);

    const int gBlocks = (N + 127) / 128;
    const int aBlocks = (N + 3) / 4;

    // ---- layer 1 ----  hp1 (bf16) aliases staging: staging dead after binB.
    gemm1_kernel<<<gBlocks, 256, 0, stream>>>(x, W1, dinv, hp, N);
    agg1_kernel<<<aBlocks, 256, 0, stream>>>(hp, esrc, rowptr, dinv, b1, h1, N);

    // ---- layer 2 ----
    gemm2_kernel<<<gBlocks, 256, 0, stream>>>(h1, W2, dinv, hp, N);
    agg2_kernel<<<aBlocks, 256, 0, stream>>>(hp, esrc, rowptr, dinv, b2, emb, N);

    // ---- FC head ----
    fc_kernel<<<gBlocks, 256, 0, stream>>>(emb, Wfc, bfc, logits, N);
}